// Round 5
// baseline (504.887 us; speedup 1.0000x reference)
//
#include <hip/hip_runtime.h>
#include <stdint.h>

#define N_ 8192
#define M_ 4096
#define FIN_ 256
#define F_ 128
#define B_ 2048

typedef __attribute__((ext_vector_type(8))) short vs8;
typedef __attribute__((ext_vector_type(8))) __bf16 vb8;
typedef __attribute__((ext_vector_type(4))) float vf4;

union ABu { vs8 s; vb8 b; };

__device__ __forceinline__ vf4 mfma16(const ABu& a, const ABu& b, vf4 c) {
    return __builtin_amdgcn_mfma_f32_16x16x32_bf16(a.b, b.b, c, 0, 0, 0);
}
__device__ __forceinline__ unsigned short f2b(float x) {
    union { float f; unsigned u; } v; v.f = x;
    unsigned r = v.u + 0x7fffu + ((v.u >> 16) & 1u);
    return (unsigned short)(r >> 16);
}
__device__ __forceinline__ float lrelu(float x) { return x > 0.f ? x : 0.2f * x; }

// ---------------- small prep: W[256][128] f32 -> WT[128][256] bf16 ----------------
__global__ void k_wprep(const float* __restrict__ W1, const float* __restrict__ W2,
                        unsigned short* __restrict__ W1T, unsigned short* __restrict__ W2T) {
    int id = blockIdx.x * 256 + threadIdx.x;            // 0..65535
    const float* W = (id < 32768) ? W1 : W2;
    unsigned short* WT = (id < 32768) ? W1T : W2T;
    int o = id & 32767;
    int f = o >> 8, k = o & 255;
    WT[o] = f2b(W[k * F_ + f]);
}

// ---- h1 = Rinput@W1, h2 = Sinput@W2 in ONE launch; 16 rows/block, 4 waves x 32f ----
__global__ __launch_bounds__(256) void k_hgemm2(const float* __restrict__ Rin, const float* __restrict__ Sin,
                                                const unsigned short* __restrict__ W1T,
                                                const unsigned short* __restrict__ W2T,
                                                float* __restrict__ h1, float* __restrict__ h2) {
    int w = threadIdx.x >> 6, l = threadIdx.x & 63;
    int lr = l & 15, lg = l >> 4;
    int gr = blockIdx.x * 16;
    const float* X; float* H; const unsigned short* WT; int row0;
    if (gr < M_) { X = Rin; H = h1; WT = W1T; row0 = gr; }
    else         { X = Sin; H = h2; WT = W2T; row0 = gr - M_; }
    int fbase = w * 32;
    vf4 acc[2] = {};
    const float* xp = X + (size_t)(row0 + lr) * FIN_ + lg * 8;
#pragma unroll
    for (int kk = 0; kk < FIN_; kk += 32) {
        float4 xa = *(const float4*)(xp + kk);
        float4 xb = *(const float4*)(xp + kk + 4);
        ABu af;
        af.s[0] = (short)f2b(xa.x); af.s[1] = (short)f2b(xa.y);
        af.s[2] = (short)f2b(xa.z); af.s[3] = (short)f2b(xa.w);
        af.s[4] = (short)f2b(xb.x); af.s[5] = (short)f2b(xb.y);
        af.s[6] = (short)f2b(xb.z); af.s[7] = (short)f2b(xb.w);
#pragma unroll
        for (int q = 0; q < 2; ++q) {
            ABu bf; bf.s = *(const vs8*)(WT + (fbase + q * 16 + lr) * FIN_ + kk + lg * 8);
            acc[q] = mfma16(af, bf, acc[q]);
        }
    }
#pragma unroll
    for (int q = 0; q < 2; ++q)
#pragma unroll
        for (int r = 0; r < 4; ++r)
            H[(size_t)(row0 + lg * 4 + r) * F_ + fbase + q * 16 + lr] = acc[q][r];
}

// ---------------- h f32 [rows][128] -> hT bf16 [128][rows], both in one launch ----------------
__global__ void k_castT2(const float* __restrict__ h1, const float* __restrict__ h2,
                         unsigned short* __restrict__ h1T, unsigned short* __restrict__ h2T) {
    __shared__ float tile[32][33];
    int bx = blockIdx.x;
    const float* Hs; unsigned short* HT; int rows, r0;
    if (bx < M_ / 32) { Hs = h1; HT = h1T; rows = M_; r0 = bx * 32; }
    else              { Hs = h2; HT = h2T; rows = N_; r0 = (bx - M_ / 32) * 32; }
    int f0 = blockIdx.y * 32;
    int tx = threadIdx.x & 31, ty = threadIdx.x >> 5;   // 32 x 8
#pragma unroll
    for (int p = 0; p < 4; ++p)
        tile[ty + p * 8][tx] = Hs[(size_t)(r0 + ty + p * 8) * F_ + f0 + tx];
    __syncthreads();
#pragma unroll
    for (int p = 0; p < 4; ++p)
        HT[(size_t)(f0 + ty + p * 8) * rows + r0 + tx] = f2b(tile[tx][ty + p * 8]);
}

// ---- s1/s2 dot products + h2wT gather in one launch ----
__global__ void k_svecgather(const float* __restrict__ h1, const float* __restrict__ h2,
                             const float* __restrict__ a, const int* __restrict__ src,
                             float* __restrict__ s1, float* __restrict__ s2,
                             unsigned short* __restrict__ h2wT) {
    if (blockIdx.x < (M_ + N_) / 4) {
        int w = threadIdx.x >> 6, l = threadIdx.x & 63;
        int row = blockIdx.x * 4 + w;
        const float* hp; const float* ap; float* sp;
        if (row < M_) { hp = h1 + (size_t)row * F_; ap = a;       sp = s1 + row; }
        else { int r = row - M_; hp = h2 + (size_t)r * F_; ap = a + F_; sp = s2 + r; }
        float v = hp[l] * ap[l] + hp[64 + l] * ap[64 + l];
        for (int off = 32; off > 0; off >>= 1) v += __shfl_down(v, off, 64);
        if (l == 0) *sp = v;
    } else {
        int gb = blockIdx.x - (M_ + N_) / 4;
        int b = gb * 2 + (threadIdx.x >> 7);
        int f = threadIdx.x & 127;
        float v = h2[(size_t)src[b] * F_ + f];
        h2wT[(size_t)f * B_ + b] = f2b(v);
    }
}

// ---- fused: inter_adj row stats+bitmask (blocks 0..N-1) + city/prov bitmask+counts ----
__global__ __launch_bounds__(256) void k_adjmask(const int* __restrict__ inter, const float* __restrict__ s1,
                                                 const float* __restrict__ s2, unsigned short* __restrict__ bm,
                                                 float* __restrict__ rowmax, float* __restrict__ rowinv,
                                                 const int* __restrict__ city, const int* __restrict__ prov,
                                                 const int* __restrict__ src,
                                                 uint32_t* __restrict__ BMtc, uint32_t* __restrict__ BMtp,
                                                 float* __restrict__ w3, float* __restrict__ w4) {
    __shared__ float wred[8];
    int t = threadIdx.x;
    int wv = t >> 6, ln = t & 63;
    if (blockIdx.x < N_) {
        // ---- adjstats ----
        int n = blockIdx.x;
        const int* rp = inter + (size_t)n * M_ + t * 16;
        float sv[16]; unsigned mask = 0;
#pragma unroll
        for (int c = 0; c < 4; ++c) {
            int4 v = *(const int4*)(rp + c * 4);
            if (v.x > 0) mask |= 1u << (c * 4 + 0);
            if (v.y > 0) mask |= 1u << (c * 4 + 1);
            if (v.z > 0) mask |= 1u << (c * 4 + 2);
            if (v.w > 0) mask |= 1u << (c * 4 + 3);
            float4 s = *(const float4*)(s1 + t * 16 + c * 4);
            sv[c * 4 + 0] = s.x; sv[c * 4 + 1] = s.y; sv[c * 4 + 2] = s.z; sv[c * 4 + 3] = s.w;
        }
        bm[(size_t)n * 256 + t] = (unsigned short)(mask & 0xffffu);
        float mx = -3.0e38f;
#pragma unroll
        for (int j = 0; j < 16; ++j) if (mask & (1u << j)) mx = fmaxf(mx, sv[j]);
        for (int off = 32; off > 0; off >>= 1) mx = fmaxf(mx, __shfl_down(mx, off, 64));
        if (ln == 0) wred[wv] = mx;
        __syncthreads();
        float s1mx = fmaxf(fmaxf(wred[0], wred[1]), fmaxf(wred[2], wred[3]));
        float s2n = s2[n];
        float rmx = lrelu(s2n + s1mx);
        float sum = 0.f;
#pragma unroll
        for (int j = 0; j < 16; ++j) if (mask & (1u << j)) sum += __expf(lrelu(s2n + sv[j]) - rmx);
        for (int off = 32; off > 0; off >>= 1) sum += __shfl_down(sum, off, 64);
        if (ln == 0) wred[4 + wv] = sum;
        __syncthreads();
        if (t == 0) {
            float tot = wred[4] + wred[5] + wred[6] + wred[7];
            bool any = s1mx > -2.9e38f;
            rowmax[n] = any ? rmx : 0.f;
            rowinv[n] = (any && tot > 0.f) ? 1.0f / tot : 0.f;
        }
    } else {
        // ---- maskcnt (transposed bitmask) ----
        int bb = blockIdx.x - N_;
        int b = bb & (B_ - 1);
        bool isC = bb < B_;
        const int* adj = isC ? city : prov;
        uint32_t* BM = isC ? BMtc : BMtp;
        float* wout = isC ? w3 : w4;
        const int* rowp = adj + (size_t)src[b] * N_;
        int cnt = 0;
#pragma unroll 4
        for (int i = 0; i < N_ / 256; ++i) {
            int v = rowp[i * 256 + t];
            unsigned long long bal = __ballot(v > 0);
            cnt += (v > 0);
            if (ln == 0) {
                int widx = i * 8 + wv * 2;
                BM[(size_t)widx * B_ + b] = (uint32_t)bal;
                BM[(size_t)(widx + 1) * B_ + b] = (uint32_t)(bal >> 32);
            }
        }
        float fc = (float)cnt;
        for (int off = 32; off > 0; off >>= 1) fc += __shfl_down(fc, off, 64);
        if (ln == 0) wred[wv] = fc;
        __syncthreads();
        if (t == 0) {
            float tot = wred[0] + wred[1] + wred[2] + wred[3];
            wout[b] = tot > 0.f ? 1.0f / tot : 0.f;
        }
    }
}

// ---- ballot bit-transpose: bm[n][m-bits] -> bmT[m][n-bits], 64x64-bit tiles ----
__global__ __launch_bounds__(256) void k_bitT(const unsigned long long* __restrict__ bm64,
                                              unsigned long long* __restrict__ bmT64) {
    int tile = blockIdx.x * 4 + (threadIdx.x >> 6);       // 8192 tiles: 128 n-tiles x 64 m-tiles
    int l = threadIdx.x & 63;
    int tn = tile >> 6, tm = tile & 63;
    unsigned long long row = bm64[(size_t)(tn * 64 + l) * 64 + tm];   // lane l = row n0+l
    unsigned long long mine = 0;
#pragma unroll
    for (int c = 0; c < 64; ++c) {
        unsigned long long b = __ballot((unsigned)((row >> c) & 1ull));
        if (l == c) mine = b;                              // ballot bit j = adj(n0+j, m0+c)
    }
    bmT64[(size_t)(tm * 64 + l) * 128 + tn] = mine;
}

// ---- uP[y] = att-slice @ h1: att regenerated on the fly from bm + s1/s2/rowmax/rowinv ----
__global__ __launch_bounds__(256) void k_gemmA2(const unsigned char* __restrict__ bm8,
                                                const float* __restrict__ s1, const float* __restrict__ s2,
                                                const float* __restrict__ rowmax, const float* __restrict__ rowinv,
                                                const unsigned short* __restrict__ h1T,
                                                float* __restrict__ uP) {
    int w = threadIdx.x >> 6, l = threadIdx.x & 63;
    int lr = l & 15, lg = l >> 4;
    int nb = blockIdx.x * 32 + (w >> 1) * 16;
    int fb = (w & 1) * 64;
    int n = nb + lr;
    float s2n = s2[n], rmx = rowmax[n], rin = rowinv[n];
    const unsigned char* bp = bm8 + (size_t)n * 512;
    vf4 acc[4] = {};
    int m0s = blockIdx.y * (M_ / 4);
    for (int m0 = m0s; m0 < m0s + M_ / 4; m0 += 32) {
        int mm = m0 + lg * 8;
        unsigned bits = bp[mm >> 3];
        float4 sa = *(const float4*)(s1 + mm);
        float4 sb = *(const float4*)(s1 + mm + 4);
        float sv[8] = {sa.x, sa.y, sa.z, sa.w, sb.x, sb.y, sb.z, sb.w};
        ABu af;
#pragma unroll
        for (int j = 0; j < 8; ++j) {
            float v = (bits & (1u << j)) ? __expf(lrelu(s2n + sv[j]) - rmx) * rin : 0.f;
            af.s[j] = (short)f2b(v);
        }
#pragma unroll
        for (int q = 0; q < 4; ++q) {
            ABu bf; bf.s = *(const vs8*)(h1T + (size_t)(fb + q * 16 + lr) * M_ + m0 + lg * 8);
            acc[q] = mfma16(af, bf, acc[q]);
        }
    }
    float* up = uP + (size_t)blockIdx.y * N_ * F_;
#pragma unroll
    for (int q = 0; q < 4; ++q)
#pragma unroll
        for (int r = 0; r < 4; ++r)
            up[(size_t)(nb + lg * 4 + r) * F_ + fb + q * 16 + lr] = acc[q][r];
}

// ---- vP[y] = att^T-slice @ h2: att regenerated from bmT (bits along n for fixed m) ----
__global__ __launch_bounds__(256) void k_gemmB2(const unsigned char* __restrict__ bmT8,
                                                const float* __restrict__ s1, const float* __restrict__ s2,
                                                const float* __restrict__ rowmax, const float* __restrict__ rowinv,
                                                const unsigned short* __restrict__ h2T,
                                                float* __restrict__ vP) {
    int w = threadIdx.x >> 6, l = threadIdx.x & 63;
    int lr = l & 15, lg = l >> 4;
    int mb = blockIdx.x * 32 + (w >> 1) * 16;
    int fb = (w & 1) * 64;
    int m = mb + lr;
    float s1m = s1[m];
    const unsigned char* bp = bmT8 + (size_t)m * 1024;
    vf4 acc[4] = {};
    int n0s = blockIdx.y * (N_ / 4);
    for (int n0 = n0s; n0 < n0s + N_ / 4; n0 += 32) {
        int nn = n0 + lg * 8;
        unsigned bits = bp[nn >> 3];
        float4 za = *(const float4*)(s2 + nn);
        float4 zb = *(const float4*)(s2 + nn + 4);
        float4 ra = *(const float4*)(rowmax + nn);
        float4 rb = *(const float4*)(rowmax + nn + 4);
        float4 ia = *(const float4*)(rowinv + nn);
        float4 ib = *(const float4*)(rowinv + nn + 4);
        float zv[8] = {za.x, za.y, za.z, za.w, zb.x, zb.y, zb.z, zb.w};
        float rv[8] = {ra.x, ra.y, ra.z, ra.w, rb.x, rb.y, rb.z, rb.w};
        float iv[8] = {ia.x, ia.y, ia.z, ia.w, ib.x, ib.y, ib.z, ib.w};
        ABu af;
#pragma unroll
        for (int j = 0; j < 8; ++j) {
            float v = (bits & (1u << j)) ? __expf(lrelu(zv[j] + s1m) - rv[j]) * iv[j] : 0.f;
            af.s[j] = (short)f2b(v);
        }
#pragma unroll
        for (int q = 0; q < 4; ++q) {
            ABu bf; bf.s = *(const vs8*)(h2T + (size_t)(fb + q * 16 + lr) * N_ + n0 + lg * 8);
            acc[q] = mfma16(af, bf, acc[q]);
        }
    }
    float* vp = vP + (size_t)blockIdx.y * M_ * F_;
#pragma unroll
    for (int q = 0; q < 4; ++q)
#pragma unroll
        for (int r = 0; r < 4; ++r)
            vp[(size_t)(mb + lg * 4 + r) * F_ + fb + q * 16 + lr] = acc[q][r];
}

// ---- uP[4+y] = G-slice @ h2w: G built on the fly from transposed city/prov bitmasks ----
__global__ __launch_bounds__(256) void k_gemmC4(const uint32_t* __restrict__ BMtc, const uint32_t* __restrict__ BMtp,
                                                const float* __restrict__ w3, const float* __restrict__ w4,
                                                const unsigned short* __restrict__ h2wT,
                                                float* __restrict__ uP) {
    int w = threadIdx.x >> 6, l = threadIdx.x & 63;
    int lr = l & 15, lg = l >> 4;
    int nb = blockIdx.x * 32 + (w >> 1) * 16;
    int fb = (w & 1) * 64;
    int n = nb + lr;
    int wi = n >> 5;
    int bitpos = n & 31;
    const uint32_t* bc = BMtc + (size_t)wi * B_;
    const uint32_t* bp = BMtp + (size_t)wi * B_;
    vf4 acc[4] = {};
    int b0s = blockIdx.y * (B_ / 2);
    for (int b0 = b0s; b0 < b0s + B_ / 2; b0 += 32) {
        int bb = b0 + lg * 8;
        uint4 c0 = *(const uint4*)(bc + bb);
        uint4 c1 = *(const uint4*)(bc + bb + 4);
        uint4 p0 = *(const uint4*)(bp + bb);
        uint4 p1 = *(const uint4*)(bp + bb + 4);
        float4 wa = *(const float4*)(w3 + bb);
        float4 wb = *(const float4*)(w3 + bb + 4);
        float4 wc = *(const float4*)(w4 + bb);
        float4 wd = *(const float4*)(w4 + bb + 4);
        uint32_t cw[8] = {c0.x, c0.y, c0.z, c0.w, c1.x, c1.y, c1.z, c1.w};
        uint32_t pw[8] = {p0.x, p0.y, p0.z, p0.w, p1.x, p1.y, p1.z, p1.w};
        float w3v[8] = {wa.x, wa.y, wa.z, wa.w, wb.x, wb.y, wb.z, wb.w};
        float w4v[8] = {wc.x, wc.y, wc.z, wc.w, wd.x, wd.y, wd.z, wd.w};
        ABu af;
#pragma unroll
        for (int j = 0; j < 8; ++j) {
            float v = (((cw[j] >> bitpos) & 1u) ? w3v[j] : 0.f) + (((pw[j] >> bitpos) & 1u) ? w4v[j] : 0.f);
            af.s[j] = (short)f2b(v);
        }
#pragma unroll
        for (int q = 0; q < 4; ++q) {
            ABu bf; bf.s = *(const vs8*)(h2wT + (size_t)(fb + q * 16 + lr) * B_ + b0 + lg * 8);
            acc[q] = mfma16(af, bf, acc[q]);
        }
    }
    float* up = uP + (size_t)(4 + blockIdx.y) * N_ * F_;
#pragma unroll
    for (int q = 0; q < 4; ++q)
#pragma unroll
        for (int r = 0; r < 4; ++r)
            up[(size_t)(nb + lg * 4 + r) * F_ + fb + q * 16 + lr] = acc[q][r];
}

// ---- sum partials -> v_in/u_in + batchnorm column stats in one pass ----
__global__ __launch_bounds__(256) void k_bnreduce(const float* __restrict__ vP, const float* __restrict__ uP,
                                                  float* __restrict__ v_in, float* __restrict__ u_in,
                                                  float* __restrict__ stats) {
    __shared__ float r1[256], r2[256];
    int bx = blockIdx.x;
    const float* P; float* O; int R, NP, step; float* sum; float* sq; size_t stride;
    if (bx < 64) { P = vP; O = v_in; R = M_; NP = 4; step = 128; stride = (size_t)M_ * F_;
                   sum = stats; sq = stats + 128; }
    else         { P = uP; O = u_in; R = N_; NP = 6; step = 256; stride = (size_t)N_ * F_;
                   sum = stats + 256; sq = stats + 384; bx -= 64; }
    int f = threadIdx.x & 127;
    int half = threadIdx.x >> 7;
    float s = 0.f, s2v = 0.f;
    for (int r = bx * 2 + half; r < R; r += step) {
        float v = 0.f;
        for (int y = 0; y < NP; ++y) v += P[(size_t)y * stride + (size_t)r * F_ + f];
        O[(size_t)r * F_ + f] = v;
        s += v; s2v += v * v;
    }
    r1[threadIdx.x] = s; r2[threadIdx.x] = s2v;
    __syncthreads();
    if (half == 0) {
        atomicAdd(&sum[f], r1[f] + r1[f + 128]);
        atomicAdd(&sq[f], r2[f] + r2[f + 128]);
    }
}

// ---------------- scale/shift from stats ----------------
__global__ void k_bnfinal(const float* __restrict__ stats, const float* __restrict__ g1,
                          const float* __restrict__ b1, const float* __restrict__ g2,
                          const float* __restrict__ b2, float* __restrict__ scsh) {
    int t = threadIdx.x;                                  // 256
    int f = t & 127;
    const float* sum; const float* sq; const float* g; const float* be; float R; float* sc; float* sh;
    if (t < 128) { sum = stats;       sq = stats + 128; g = g1; be = b1; R = 4096.f; sc = scsh;       sh = scsh + 128; }
    else         { sum = stats + 256; sq = stats + 384; g = g2; be = b2; R = 8192.f; sc = scsh + 256; sh = scsh + 384; }
    float mean = sum[f] / R;
    float var = sq[f] / R - mean * mean;
    float s = g[f] * rsqrtf(var + 1e-5f);
    sc[f] = s; sh[f] = be[f] - mean * s;
}

// ---------------- apply bn + leaky + cast bf16, both matrices in one launch ----------------
__global__ void k_bnapply2(const float* __restrict__ v_in, const float* __restrict__ u_in,
                           const float* __restrict__ scsh,
                           unsigned short* __restrict__ v_outb, unsigned short* __restrict__ u_outb) {
    int id = blockIdx.x * 256 + threadIdx.x;
    const float* P; unsigned short* Q; int which, idx;
    if (id < M_ * F_) { P = v_in; Q = v_outb; which = 0; idx = id; }
    else              { P = u_in; Q = u_outb; which = 1; idx = id - M_ * F_; }
    int f = idx & 127;
    float s = scsh[which * 256 + f], sh = scsh[which * 256 + 128 + f];
    Q[idx] = f2b(lrelu(P[idx] * s + sh));
}

// ---------------- out = elu(U @ V^T) ----------------
__global__ __launch_bounds__(256) void k_gemmD(const unsigned short* __restrict__ U,
                                               const unsigned short* __restrict__ V,
                                               float* __restrict__ out) {
    int w = threadIdx.x >> 6, l = threadIdx.x & 63;
    int lr = l & 15, lg = l >> 4;
    int nb = blockIdx.x * 64 + w * 16;
    int mb = blockIdx.y * 64;
    vf4 acc[4] = {};
#pragma unroll
    for (int k0 = 0; k0 < F_; k0 += 32) {
        ABu af; af.s = *(const vs8*)(U + (size_t)(nb + lr) * F_ + k0 + lg * 8);
#pragma unroll
        for (int q = 0; q < 4; ++q) {
            ABu bf; bf.s = *(const vs8*)(V + (size_t)(mb + q * 16 + lr) * F_ + k0 + lg * 8);
            acc[q] = mfma16(af, bf, acc[q]);
        }
    }
#pragma unroll
    for (int q = 0; q < 4; ++q)
#pragma unroll
        for (int r = 0; r < 4; ++r) {
            int row = nb + lg * 4 + r;
            int col = mb + q * 16 + lr;
            float x = acc[q][r];
            out[(size_t)row * M_ + col] = x > 0.f ? x : __expf(x) - 1.f;
        }
}

extern "C" void kernel_launch(void* const* d_in, const int* in_sizes, int n_in,
                              void* d_out, int out_size, void* d_ws, size_t ws_size,
                              hipStream_t stream) {
    const float* Sinput = (const float*)d_in[0];
    const float* Rinput = (const float*)d_in[1];
    const int* inter_adj = (const int*)d_in[2];
    const int* city_adj = (const int*)d_in[3];
    const int* prov_adj = (const int*)d_in[4];
    const int* src = (const int*)d_in[5];
    const float* W1 = (const float*)d_in[6];
    const float* W2 = (const float*)d_in[7];
    const float* a = (const float*)d_in[8];
    const float* g1 = (const float*)d_in[11];
    const float* b1 = (const float*)d_in[12];
    const float* g2 = (const float*)d_in[13];
    const float* b2 = (const float*)d_in[14];
    float* out = (float*)d_out;

    char* ws = (char*)d_ws;
    size_t o = 0;
    auto take = [&](size_t bytes) { char* p = ws + o; o += (bytes + 255) & ~(size_t)255; return p; };
    float* stats = (float*)take(512 * 4);
    size_t zero_bytes = o;                               // only stats zeroed each launch
    float* u_in = (float*)take((size_t)N_ * F_ * 4);
    float* v_in = (float*)take((size_t)M_ * F_ * 4);
    float* uP = (float*)take((size_t)6 * N_ * F_ * 4);
    float* vP = (float*)take((size_t)4 * M_ * F_ * 4);
    float* h1 = (float*)take((size_t)M_ * F_ * 4);
    float* h2 = (float*)take((size_t)N_ * F_ * 4);
    unsigned short* h1T = (unsigned short*)take((size_t)F_ * M_ * 2);
    unsigned short* h2T = (unsigned short*)take((size_t)F_ * N_ * 2);
    unsigned short* W1T = (unsigned short*)take((size_t)F_ * FIN_ * 2);
    unsigned short* W2T = (unsigned short*)take((size_t)F_ * FIN_ * 2);
    float* s1 = (float*)take(M_ * 4);
    float* s2 = (float*)take(N_ * 4);
    float* rowmax = (float*)take(N_ * 4);
    float* rowinv = (float*)take(N_ * 4);
    float* w3 = (float*)take(B_ * 4);
    float* w4 = (float*)take(B_ * 4);
    unsigned short* h2wT = (unsigned short*)take((size_t)F_ * B_ * 2);
    float* scsh = (float*)take(512 * 4);
    unsigned short* u_outb = (unsigned short*)take((size_t)N_ * F_ * 2);
    unsigned short* v_outb = (unsigned short*)take((size_t)M_ * F_ * 2);
    uint32_t* BMtc = (uint32_t*)take((size_t)256 * B_ * 4);
    uint32_t* BMtp = (uint32_t*)take((size_t)256 * B_ * 4);
    unsigned short* bm = (unsigned short*)take((size_t)N_ * 256 * 2);      // 4 MB, [n][m-bits]
    unsigned short* bmT = (unsigned short*)take((size_t)M_ * 512 * 2);     // 4 MB, [m][n-bits]
    (void)ws_size; (void)in_sizes; (void)n_in; (void)out_size;

    hipMemsetAsync(d_ws, 0, zero_bytes, stream);

    k_wprep<<<256, 256, 0, stream>>>(W1, W2, W1T, W2T);
    k_hgemm2<<<(M_ + N_) / 16, 256, 0, stream>>>(Rinput, Sinput, W1T, W2T, h1, h2);
    k_castT2<<<dim3((M_ + N_) / 32, 4), 256, 0, stream>>>(h1, h2, h1T, h2T);
    k_svecgather<<<(M_ + N_) / 4 + B_ / 2, 256, 0, stream>>>(h1, h2, a, src, s1, s2, h2wT);
    k_adjmask<<<N_ + 2 * B_, 256, 0, stream>>>(inter_adj, s1, s2, bm, rowmax, rowinv,
                                               city_adj, prov_adj, src, BMtc, BMtp, w3, w4);
    k_bitT<<<2048, 256, 0, stream>>>((const unsigned long long*)bm, (unsigned long long*)bmT);
    k_gemmA2<<<dim3(N_ / 32, 4), 256, 0, stream>>>((const unsigned char*)bm, s1, s2, rowmax, rowinv, h1T, uP);
    k_gemmB2<<<dim3(M_ / 32, 4), 256, 0, stream>>>((const unsigned char*)bmT, s1, s2, rowmax, rowinv, h2T, vP);
    k_gemmC4<<<dim3(N_ / 32, 2), 256, 0, stream>>>(BMtc, BMtp, w3, w4, h2wT, uP);
    k_bnreduce<<<192, 256, 0, stream>>>(vP, uP, v_in, u_in, stats);
    k_bnfinal<<<1, 256, 0, stream>>>(stats, g1, b1, g2, b2, scsh);
    k_bnapply2<<<(M_ + N_) * F_ / 256, 256, 0, stream>>>(v_in, u_in, scsh, v_outb, u_outb);
    k_gemmD<<<dim3(N_ / 64, M_ / 64), 256, 0, stream>>>(u_outb, v_outb, out);
}

// Round 6
// 417.836 us; speedup vs baseline: 1.2083x; 1.2083x over previous
//
#include <hip/hip_runtime.h>
#include <stdint.h>

#define N_ 8192
#define M_ 4096
#define FIN_ 256
#define F_ 128
#define B_ 2048

typedef __attribute__((ext_vector_type(8))) short vs8;
typedef __attribute__((ext_vector_type(8))) __bf16 vb8;
typedef __attribute__((ext_vector_type(4))) float vf4;

union ABu { vs8 s; vb8 b; };

__device__ __forceinline__ vf4 mfma16(const ABu& a, const ABu& b, vf4 c) {
    return __builtin_amdgcn_mfma_f32_16x16x32_bf16(a.b, b.b, c, 0, 0, 0);
}
__device__ __forceinline__ unsigned short f2b(float x) {
    union { float f; unsigned u; } v; v.f = x;
    unsigned r = v.u + 0x7fffu + ((v.u >> 16) & 1u);
    return (unsigned short)(r >> 16);
}
__device__ __forceinline__ float lrelu(float x) { return x > 0.f ? x : 0.2f * x; }

// ---------------- small prep: W[256][128] f32 -> WT[128][256] bf16 ----------------
__global__ void k_wprep(const float* __restrict__ W1, const float* __restrict__ W2,
                        unsigned short* __restrict__ W1T, unsigned short* __restrict__ W2T) {
    int id = blockIdx.x * 256 + threadIdx.x;            // 0..65535
    const float* W = (id < 32768) ? W1 : W2;
    unsigned short* WT = (id < 32768) ? W1T : W2T;
    int o = id & 32767;
    int f = o >> 8, k = o & 255;
    WT[o] = f2b(W[k * F_ + f]);
}

// ---- FUSED: h = X@W (MFMA), write h2 f32, write hT bf16 (LDS transpose), s1/s2 row-dots ----
__global__ __launch_bounds__(256) void k_hgemmF(const float* __restrict__ Rin, const float* __restrict__ Sin,
                                                const unsigned short* __restrict__ W1T,
                                                const unsigned short* __restrict__ W2T,
                                                const float* __restrict__ a,
                                                float* __restrict__ h2,
                                                unsigned short* __restrict__ h1T, unsigned short* __restrict__ h2T,
                                                float* __restrict__ s1, float* __restrict__ s2) {
    __shared__ unsigned short tb[16][136];               // 16 rows x 128 f, padded
    __shared__ float sred[4][16];
    int t = threadIdx.x;
    int w = t >> 6, l = t & 63, lr = l & 15, lg = l >> 4;
    int gr = blockIdx.x * 16;
    const float* X; const unsigned short* WT; unsigned short* HT; float* sout; const float* av;
    int row0, rows; bool isH2;
    if (gr < M_) { X = Rin; WT = W1T; HT = h1T; sout = s1; av = a;      row0 = gr;      rows = M_; isH2 = false; }
    else         { X = Sin; WT = W2T; HT = h2T; sout = s2; av = a + F_; row0 = gr - M_; rows = N_; isH2 = true;  }
    int fbase = w * 32;
    vf4 acc[2] = {};
    const float* xp = X + (size_t)(row0 + lr) * FIN_ + lg * 8;
#pragma unroll
    for (int kk = 0; kk < FIN_; kk += 32) {
        float4 xa = *(const float4*)(xp + kk);
        float4 xb = *(const float4*)(xp + kk + 4);
        ABu af;
        af.s[0] = (short)f2b(xa.x); af.s[1] = (short)f2b(xa.y);
        af.s[2] = (short)f2b(xa.z); af.s[3] = (short)f2b(xa.w);
        af.s[4] = (short)f2b(xb.x); af.s[5] = (short)f2b(xb.y);
        af.s[6] = (short)f2b(xb.z); af.s[7] = (short)f2b(xb.w);
#pragma unroll
        for (int q = 0; q < 2; ++q) {
            ABu bf; bf.s = *(const vs8*)(WT + (fbase + q * 16 + lr) * FIN_ + kk + lg * 8);
            acc[q] = mfma16(af, bf, acc[q]);
        }
    }
    // h2 f32 (needed by the h2wT gather); h1 f32 is never consumed -> skip
    if (isH2) {
#pragma unroll
        for (int q = 0; q < 2; ++q)
#pragma unroll
            for (int r = 0; r < 4; ++r)
                h2[(size_t)(row0 + lg * 4 + r) * F_ + fbase + q * 16 + lr] = acc[q][r];
    }
    // stage bf16 tile for transposed HT write
#pragma unroll
    for (int q = 0; q < 2; ++q)
#pragma unroll
        for (int r = 0; r < 4; ++r)
            tb[lg * 4 + r][fbase + q * 16 + lr] = f2b(acc[q][r]);
    // s row-dot: sum over this wave's 32 columns, then cross-wave via LDS
    float a0 = av[fbase + lr], a1 = av[fbase + 16 + lr];
    float tv[4];
#pragma unroll
    for (int r = 0; r < 4; ++r) tv[r] = acc[0][r] * a0 + acc[1][r] * a1;
#pragma unroll
    for (int off = 1; off < 16; off <<= 1)
#pragma unroll
        for (int r = 0; r < 4; ++r) tv[r] += __shfl_xor(tv[r], off, 64);
    if ((l & 15) == 0)
#pragma unroll
        for (int r = 0; r < 4; ++r) sred[w][lg * 4 + r] = tv[r];
    __syncthreads();
    // HT[f][row0..row0+16): 2 threads per f, 16B each
    {
        int f = t >> 1, half = t & 1;
        vs8 o;
#pragma unroll
        for (int j = 0; j < 8; ++j) o[j] = (short)tb[half * 8 + j][f];
        *(vs8*)(HT + (size_t)f * rows + row0 + half * 8) = o;
    }
    if (t < 16) {
        float s = sred[0][t] + sred[1][t] + sred[2][t] + sred[3][t];
        sout[row0 + t] = s;
    }
}

// ---- FUSED: inter stats+bitmask | city/prov bitmask+counts | h2wT gather ----
__global__ __launch_bounds__(256) void k_adjgather(const int* __restrict__ inter, const float* __restrict__ s1,
                                                   const float* __restrict__ s2, unsigned short* __restrict__ bm,
                                                   float* __restrict__ rowmax, float* __restrict__ rowinv,
                                                   const int* __restrict__ city, const int* __restrict__ prov,
                                                   const int* __restrict__ src,
                                                   uint32_t* __restrict__ BMtc, uint32_t* __restrict__ BMtp,
                                                   float* __restrict__ w3, float* __restrict__ w4,
                                                   const float* __restrict__ h2, unsigned short* __restrict__ h2wT) {
    __shared__ float wred[8];
    int t = threadIdx.x;
    int wv = t >> 6, ln = t & 63;
    if (blockIdx.x < N_) {
        // ---- inter_adj row stats ----
        int n = blockIdx.x;
        const int* rp = inter + (size_t)n * M_ + t * 16;
        float sv[16]; unsigned mask = 0;
#pragma unroll
        for (int c = 0; c < 4; ++c) {
            int4 v = *(const int4*)(rp + c * 4);
            if (v.x > 0) mask |= 1u << (c * 4 + 0);
            if (v.y > 0) mask |= 1u << (c * 4 + 1);
            if (v.z > 0) mask |= 1u << (c * 4 + 2);
            if (v.w > 0) mask |= 1u << (c * 4 + 3);
            float4 s = *(const float4*)(s1 + t * 16 + c * 4);
            sv[c * 4 + 0] = s.x; sv[c * 4 + 1] = s.y; sv[c * 4 + 2] = s.z; sv[c * 4 + 3] = s.w;
        }
        bm[(size_t)n * 256 + t] = (unsigned short)(mask & 0xffffu);
        float mx = -3.0e38f;
#pragma unroll
        for (int j = 0; j < 16; ++j) if (mask & (1u << j)) mx = fmaxf(mx, sv[j]);
        for (int off = 32; off > 0; off >>= 1) mx = fmaxf(mx, __shfl_down(mx, off, 64));
        if (ln == 0) wred[wv] = mx;
        __syncthreads();
        float s1mx = fmaxf(fmaxf(wred[0], wred[1]), fmaxf(wred[2], wred[3]));
        float s2n = s2[n];
        float rmx = lrelu(s2n + s1mx);
        float sum = 0.f;
#pragma unroll
        for (int j = 0; j < 16; ++j) if (mask & (1u << j)) sum += __expf(lrelu(s2n + sv[j]) - rmx);
        for (int off = 32; off > 0; off >>= 1) sum += __shfl_down(sum, off, 64);
        if (ln == 0) wred[4 + wv] = sum;
        __syncthreads();
        if (t == 0) {
            float tot = wred[4] + wred[5] + wred[6] + wred[7];
            bool any = s1mx > -2.9e38f;
            rowmax[n] = any ? rmx : 0.f;
            rowinv[n] = (any && tot > 0.f) ? 1.0f / tot : 0.f;
        }
    } else if (blockIdx.x < N_ + 2 * B_) {
        // ---- city/prov transposed bitmask + counts ----
        int bb = blockIdx.x - N_;
        int b = bb & (B_ - 1);
        bool isC = bb < B_;
        const int* adj = isC ? city : prov;
        uint32_t* BM = isC ? BMtc : BMtp;
        float* wout = isC ? w3 : w4;
        const int* rowp = adj + (size_t)src[b] * N_;
        int cnt = 0;
#pragma unroll 4
        for (int i = 0; i < N_ / 256; ++i) {
            int v = rowp[i * 256 + t];
            unsigned long long bal = __ballot(v > 0);
            cnt += (v > 0);
            if (ln == 0) {
                int widx = i * 8 + wv * 2;
                BM[(size_t)widx * B_ + b] = (uint32_t)bal;
                BM[(size_t)(widx + 1) * B_ + b] = (uint32_t)(bal >> 32);
            }
        }
        float fc = (float)cnt;
        for (int off = 32; off > 0; off >>= 1) fc += __shfl_down(fc, off, 64);
        if (ln == 0) wred[wv] = fc;
        __syncthreads();
        if (t == 0) {
            float tot = wred[0] + wred[1] + wred[2] + wred[3];
            wout[b] = tot > 0.f ? 1.0f / tot : 0.f;
        }
    } else {
        // ---- h2wT gather ----
        int gb = blockIdx.x - (N_ + 2 * B_);
        int b = gb * 2 + (t >> 7);
        int f = t & 127;
        float v = h2[(size_t)src[b] * F_ + f];
        h2wT[(size_t)f * B_ + b] = f2b(v);
    }
}

// ---------------- materialize att bf16 [N][M] ----------------
__global__ __launch_bounds__(256) void k_attmat(const unsigned char* __restrict__ bm8,
                                                const float* __restrict__ s1, const float* __restrict__ s2,
                                                const float* __restrict__ rowmax, const float* __restrict__ rowinv,
                                                unsigned short* __restrict__ att) {
    int id = blockIdx.x * 256 + threadIdx.x;             // N*M/8 threads
    int n = id >> 9;
    int m = (id & 511) * 8;
    unsigned bits = bm8[(size_t)n * 512 + (m >> 3)];
    float s2n = s2[n], rmx = rowmax[n], rin = rowinv[n];
    float4 sa = *(const float4*)(s1 + m);
    float4 sb = *(const float4*)(s1 + m + 4);
    float sv[8] = {sa.x, sa.y, sa.z, sa.w, sb.x, sb.y, sb.z, sb.w};
    vs8 o;
#pragma unroll
    for (int j = 0; j < 8; ++j) {
        float v = (bits & (1u << j)) ? __expf(lrelu(s2n + sv[j]) - rmx) * rin : 0.f;
        o[j] = (short)f2b(v);
    }
    *(vs8*)(att + (size_t)n * M_ + m) = o;
}

// ---- MERGED gemmA | gemmB | gemmC in one dispatch (block ranges), atomic accumulate ----
__global__ __launch_bounds__(256) void k_gemmABC(const unsigned short* __restrict__ att,
                                                 const unsigned short* __restrict__ h1T,
                                                 const unsigned short* __restrict__ h2T,
                                                 const uint32_t* __restrict__ BMtc, const uint32_t* __restrict__ BMtp,
                                                 const float* __restrict__ w3, const float* __restrict__ w4,
                                                 const unsigned short* __restrict__ h2wT,
                                                 float* __restrict__ u_in, float* __restrict__ v_in) {
    __shared__ unsigned short lds[32][34];
    int t = threadIdx.x;
    int w = t >> 6, l = t & 63;
    int lr = l & 15, lg = l >> 4;
    int bx = blockIdx.x;
    if (bx < 1024) {
        // ---- gemmA: u_in += att @ h1 (K-slice M/4) ----
        int xa = bx & 255, ya = bx >> 8;
        int nb = xa * 32 + (w >> 1) * 16;
        int fb = (w & 1) * 64;
        vf4 acc[4] = {};
        const unsigned short* ap = att + (size_t)(nb + lr) * M_ + lg * 8;
        int m0s = ya * (M_ / 4);
        for (int m0 = m0s; m0 < m0s + M_ / 4; m0 += 32) {
            ABu af; af.s = *(const vs8*)(ap + m0);
#pragma unroll
            for (int q = 0; q < 4; ++q) {
                ABu bf; bf.s = *(const vs8*)(h1T + (size_t)(fb + q * 16 + lr) * M_ + m0 + lg * 8);
                acc[q] = mfma16(af, bf, acc[q]);
            }
        }
#pragma unroll
        for (int q = 0; q < 4; ++q)
#pragma unroll
            for (int r = 0; r < 4; ++r)
                atomicAdd(&u_in[(size_t)(nb + lg * 4 + r) * F_ + fb + q * 16 + lr], acc[q][r]);
    } else if (bx < 1536) {
        // ---- gemmB: v_in += att.T @ h2 via LDS transpose (K-slice N/4) ----
        int i = bx - 1024;
        int xb = i & 127, yb = i >> 7;
        int mb = xb * 32;
        int mh = (w >> 1) * 16;
        int fb = (w & 1) * 64;
        int si = t >> 3;
        int sc = (t & 7) * 4;
        vf4 acc[4] = {};
        int n0s = yb * (N_ / 4);
        for (int n0 = n0s; n0 < n0s + N_ / 4; n0 += 32) {
            uint2 dv = *(const uint2*)(att + (size_t)(n0 + si) * M_ + mb + sc);
            __syncthreads();
            lds[sc + 0][si] = (unsigned short)(dv.x & 0xffffu);
            lds[sc + 1][si] = (unsigned short)(dv.x >> 16);
            lds[sc + 2][si] = (unsigned short)(dv.y & 0xffffu);
            lds[sc + 3][si] = (unsigned short)(dv.y >> 16);
            __syncthreads();
            ABu af; af.s = *(const vs8*)&lds[mh + lr][lg * 8];
#pragma unroll
            for (int q = 0; q < 4; ++q) {
                ABu bf; bf.s = *(const vs8*)(h2T + (size_t)(fb + q * 16 + lr) * N_ + n0 + lg * 8);
                acc[q] = mfma16(af, bf, acc[q]);
            }
        }
#pragma unroll
        for (int q = 0; q < 4; ++q)
#pragma unroll
            for (int r = 0; r < 4; ++r)
                atomicAdd(&v_in[(size_t)(mb + mh + lg * 4 + r) * F_ + fb + q * 16 + lr], acc[q][r]);
    } else {
        // ---- gemmC: u_in += G @ h2w, G on-the-fly from transposed bitmasks (K-slice B/2) ----
        int i = bx - 1536;
        int xc = i & 255, yc = i >> 8;
        int nb = xc * 32 + (w >> 1) * 16;
        int fb = (w & 1) * 64;
        int n = nb + lr;
        int wi = n >> 5;
        int bitpos = n & 31;
        const uint32_t* bc = BMtc + (size_t)wi * B_;
        const uint32_t* bp = BMtp + (size_t)wi * B_;
        vf4 acc[4] = {};
        int b0s = yc * (B_ / 2);
        for (int b0 = b0s; b0 < b0s + B_ / 2; b0 += 32) {
            int bb = b0 + lg * 8;
            uint4 c0 = *(const uint4*)(bc + bb);
            uint4 c1 = *(const uint4*)(bc + bb + 4);
            uint4 p0 = *(const uint4*)(bp + bb);
            uint4 p1 = *(const uint4*)(bp + bb + 4);
            float4 wa = *(const float4*)(w3 + bb);
            float4 wb = *(const float4*)(w3 + bb + 4);
            float4 wc = *(const float4*)(w4 + bb);
            float4 wd = *(const float4*)(w4 + bb + 4);
            uint32_t cw[8] = {c0.x, c0.y, c0.z, c0.w, c1.x, c1.y, c1.z, c1.w};
            uint32_t pw[8] = {p0.x, p0.y, p0.z, p0.w, p1.x, p1.y, p1.z, p1.w};
            float w3v[8] = {wa.x, wa.y, wa.z, wa.w, wb.x, wb.y, wb.z, wb.w};
            float w4v[8] = {wc.x, wc.y, wc.z, wc.w, wd.x, wd.y, wd.z, wd.w};
            ABu af;
#pragma unroll
            for (int j = 0; j < 8; ++j) {
                float v = (((cw[j] >> bitpos) & 1u) ? w3v[j] : 0.f) + (((pw[j] >> bitpos) & 1u) ? w4v[j] : 0.f);
                af.s[j] = (short)f2b(v);
            }
#pragma unroll
            for (int q = 0; q < 4; ++q) {
                ABu bf; bf.s = *(const vs8*)(h2wT + (size_t)(fb + q * 16 + lr) * B_ + b0 + lg * 8);
                acc[q] = mfma16(af, bf, acc[q]);
            }
        }
#pragma unroll
        for (int q = 0; q < 4; ++q)
#pragma unroll
            for (int r = 0; r < 4; ++r)
                atomicAdd(&u_in[(size_t)(nb + lg * 4 + r) * F_ + fb + q * 16 + lr], acc[q][r]);
    }
}

// ---------------- batchnorm column stats, both matrices in one launch ----------------
__global__ __launch_bounds__(256) void k_bnstats2(const float* __restrict__ v_in, const float* __restrict__ u_in,
                                                  float* __restrict__ stats) {
    __shared__ float r1[256], r2[256];
    int bx = blockIdx.x;
    const float* P; int R; float* sum; float* sq;
    if (bx < 128) { P = v_in; R = M_; sum = stats;       sq = stats + 128; }
    else          { P = u_in; R = N_; sum = stats + 256; sq = stats + 384; bx -= 128; }
    int f = threadIdx.x & 127;
    int half = threadIdx.x >> 7;
    float s = 0.f, s2v = 0.f;
    for (int r = bx * 2 + half; r < R; r += 256) {
        float v = P[(size_t)r * F_ + f];
        s += v; s2v += v * v;
    }
    r1[threadIdx.x] = s; r2[threadIdx.x] = s2v;
    __syncthreads();
    if (half == 0) {
        atomicAdd(&sum[f], r1[f] + r1[f + 128]);
        atomicAdd(&sq[f], r2[f] + r2[f + 128]);
    }
}

// ---- bn finalize (per-block recompute) + apply + leaky + cast bf16, float4-vectorized ----
__global__ __launch_bounds__(256) void k_bnapplyF(const float* __restrict__ v_in, const float* __restrict__ u_in,
                                                  const float* __restrict__ stats,
                                                  const float* __restrict__ g1, const float* __restrict__ b1,
                                                  const float* __restrict__ g2, const float* __restrict__ b2,
                                                  unsigned short* __restrict__ v_outb, unsigned short* __restrict__ u_outb) {
    __shared__ float sc[256], sh[256];                    // [which*128+f]
    int t = threadIdx.x;
    {
        int which = t >> 7, f = t & 127;
        const float* sum = stats + which * 256;
        const float* sq = sum + 128;
        const float* g = which ? g2 : g1;
        const float* be = which ? b2 : b1;
        float R = which ? (float)N_ : (float)M_;
        float mean = sum[f] / R;
        float var = sq[f] / R - mean * mean;
        float s = g[f] * rsqrtf(var + 1e-5f);
        sc[t] = s; sh[t] = be[f] - mean * s;
    }
    __syncthreads();
    int id4 = blockIdx.x * 256 + t;                       // one float4 per thread
    int idx = id4 * 4;
    int which = idx >= M_ * F_;
    int rel = which ? idx - M_ * F_ : idx;
    const float* P = which ? u_in : v_in;
    unsigned short* Q = which ? u_outb : v_outb;
    int f0 = (rel & 127) + which * 128;
    float4 p = *(const float4*)(P + rel);
    ushort4 o;
    o.x = f2b(lrelu(p.x * sc[f0 + 0] + sh[f0 + 0]));
    o.y = f2b(lrelu(p.y * sc[f0 + 1] + sh[f0 + 1]));
    o.z = f2b(lrelu(p.z * sc[f0 + 2] + sh[f0 + 2]));
    o.w = f2b(lrelu(p.w * sc[f0 + 3] + sh[f0 + 3]));
    *(ushort4*)(Q + rel) = o;
}

// ---------------- out = elu(U @ V^T) ----------------
__global__ __launch_bounds__(256) void k_gemmD(const unsigned short* __restrict__ U,
                                               const unsigned short* __restrict__ V,
                                               float* __restrict__ out) {
    int w = threadIdx.x >> 6, l = threadIdx.x & 63;
    int lr = l & 15, lg = l >> 4;
    int nb = blockIdx.x * 64 + w * 16;
    int mb = blockIdx.y * 64;
    vf4 acc[4] = {};
#pragma unroll
    for (int k0 = 0; k0 < F_; k0 += 32) {
        ABu af; af.s = *(const vs8*)(U + (size_t)(nb + lr) * F_ + k0 + lg * 8);
#pragma unroll
        for (int q = 0; q < 4; ++q) {
            ABu bf; bf.s = *(const vs8*)(V + (size_t)(mb + q * 16 + lr) * F_ + k0 + lg * 8);
            acc[q] = mfma16(af, bf, acc[q]);
        }
    }
#pragma unroll
    for (int q = 0; q < 4; ++q)
#pragma unroll
        for (int r = 0; r < 4; ++r) {
            int row = nb + lg * 4 + r;
            int col = mb + q * 16 + lr;
            float x = acc[q][r];
            out[(size_t)row * M_ + col] = x > 0.f ? x : __expf(x) - 1.f;
        }
}

extern "C" void kernel_launch(void* const* d_in, const int* in_sizes, int n_in,
                              void* d_out, int out_size, void* d_ws, size_t ws_size,
                              hipStream_t stream) {
    const float* Sinput = (const float*)d_in[0];
    const float* Rinput = (const float*)d_in[1];
    const int* inter_adj = (const int*)d_in[2];
    const int* city_adj = (const int*)d_in[3];
    const int* prov_adj = (const int*)d_in[4];
    const int* src = (const int*)d_in[5];
    const float* W1 = (const float*)d_in[6];
    const float* W2 = (const float*)d_in[7];
    const float* a = (const float*)d_in[8];
    const float* g1 = (const float*)d_in[11];
    const float* b1 = (const float*)d_in[12];
    const float* g2 = (const float*)d_in[13];
    const float* b2 = (const float*)d_in[14];
    float* out = (float*)d_out;

    char* ws = (char*)d_ws;
    size_t o = 0;
    auto take = [&](size_t bytes) { char* p = ws + o; o += (bytes + 255) & ~(size_t)255; return p; };
    float* u_in = (float*)take((size_t)N_ * F_ * 4);
    float* v_in = (float*)take((size_t)M_ * F_ * 4);
    float* stats = (float*)take(512 * 4);
    size_t zero_bytes = o;                               // u_in + v_in + stats zeroed each launch
    float* h2 = (float*)take((size_t)N_ * F_ * 4);
    unsigned short* h1T = (unsigned short*)take((size_t)F_ * M_ * 2);
    unsigned short* h2T = (unsigned short*)take((size_t)F_ * N_ * 2);
    unsigned short* W1T = (unsigned short*)take((size_t)F_ * FIN_ * 2);
    unsigned short* W2T = (unsigned short*)take((size_t)F_ * FIN_ * 2);
    float* s1 = (float*)take(M_ * 4);
    float* s2 = (float*)take(N_ * 4);
    float* rowmax = (float*)take(N_ * 4);
    float* rowinv = (float*)take(N_ * 4);
    float* w3 = (float*)take(B_ * 4);
    float* w4 = (float*)take(B_ * 4);
    unsigned short* h2wT = (unsigned short*)take((size_t)F_ * B_ * 2);
    unsigned short* u_outb = (unsigned short*)take((size_t)N_ * F_ * 2);
    unsigned short* v_outb = (unsigned short*)take((size_t)M_ * F_ * 2);
    uint32_t* BMtc = (uint32_t*)take((size_t)256 * B_ * 4);
    uint32_t* BMtp = (uint32_t*)take((size_t)256 * B_ * 4);
    unsigned short* bm = (unsigned short*)take((size_t)N_ * 256 * 2);      // 4 MB, [n][m-bits]
    unsigned short* att = (unsigned short*)take((size_t)N_ * M_ * 2);
    (void)ws_size; (void)in_sizes; (void)n_in; (void)out_size;

    hipMemsetAsync(d_ws, 0, zero_bytes, stream);

    k_wprep<<<256, 256, 0, stream>>>(W1, W2, W1T, W2T);
    k_hgemmF<<<(M_ + N_) / 16, 256, 0, stream>>>(Rinput, Sinput, W1T, W2T, a, h2, h1T, h2T, s1, s2);
    k_adjgather<<<N_ + 2 * B_ + B_ / 2, 256, 0, stream>>>(inter_adj, s1, s2, bm, rowmax, rowinv,
                                                          city_adj, prov_adj, src, BMtc, BMtp, w3, w4,
                                                          h2, h2wT);
    k_attmat<<<(size_t)N_ * M_ / 8 / 256, 256, 0, stream>>>((const unsigned char*)bm, s1, s2, rowmax, rowinv, att);
    k_gemmABC<<<2048, 256, 0, stream>>>(att, h1T, h2T, BMtc, BMtp, w3, w4, h2wT, u_in, v_in);
    k_bnstats2<<<256, 256, 0, stream>>>(v_in, u_in, stats);
    k_bnapplyF<<<(M_ + N_) * F_ / 4 / 256, 256, 0, stream>>>(v_in, u_in, stats, g1, b1, g2, b2, v_outb, u_outb);
    k_gemmD<<<dim3(N_ / 64, M_ / 64), 256, 0, stream>>>(u_outb, v_outb, out);
}

// Round 7
// 354.070 us; speedup vs baseline: 1.4260x; 1.1801x over previous
//
#include <hip/hip_runtime.h>
#include <stdint.h>

#define N_ 8192
#define M_ 4096
#define FIN_ 256
#define F_ 128
#define B_ 2048

typedef __attribute__((ext_vector_type(8))) short vs8;
typedef __attribute__((ext_vector_type(8))) __bf16 vb8;
typedef __attribute__((ext_vector_type(4))) float vf4;

union ABu { vs8 s; vb8 b; };

__device__ __forceinline__ vf4 mfma16(const ABu& a, const ABu& b, vf4 c) {
    return __builtin_amdgcn_mfma_f32_16x16x32_bf16(a.b, b.b, c, 0, 0, 0);
}
__device__ __forceinline__ unsigned short f2b(float x) {
    union { float f; unsigned u; } v; v.f = x;
    unsigned r = v.u + 0x7fffu + ((v.u >> 16) & 1u);
    return (unsigned short)(r >> 16);
}
__device__ __forceinline__ float lrelu(float x) { return x > 0.f ? x : 0.2f * x; }

// ---------------- small prep: W[256][128] f32 -> WT[128][256] bf16 ----------------
__global__ void k_wprep(const float* __restrict__ W1, const float* __restrict__ W2,
                        unsigned short* __restrict__ W1T, unsigned short* __restrict__ W2T) {
    int id = blockIdx.x * 256 + threadIdx.x;            // 0..65535
    const float* W = (id < 32768) ? W1 : W2;
    unsigned short* WT = (id < 32768) ? W1T : W2T;
    int o = id & 32767;
    int f = o >> 8, k = o & 255;
    WT[o] = f2b(W[k * F_ + f]);
}

// ---- FUSED: h = X@W (MFMA); write h2 f32, packed hP[kblk][f][32] bf16, s1/s2 row-dots ----
__global__ __launch_bounds__(256) void k_hgemmF(const float* __restrict__ Rin, const float* __restrict__ Sin,
                                                const unsigned short* __restrict__ W1T,
                                                const unsigned short* __restrict__ W2T,
                                                const float* __restrict__ a,
                                                float* __restrict__ h2,
                                                unsigned short* __restrict__ h1P, unsigned short* __restrict__ h2P,
                                                float* __restrict__ s1, float* __restrict__ s2) {
    __shared__ unsigned short tb[16][136];               // 16 rows x 128 f, padded
    __shared__ float sred[4][16];
    int t = threadIdx.x;
    int w = t >> 6, l = t & 63, lr = l & 15, lg = l >> 4;
    int gr = blockIdx.x * 16;
    const float* X; const unsigned short* WT; unsigned short* HP; float* sout; const float* av;
    int row0; bool isH2;
    if (gr < M_) { X = Rin; WT = W1T; HP = h1P; sout = s1; av = a;      row0 = gr;      isH2 = false; }
    else         { X = Sin; WT = W2T; HP = h2P; sout = s2; av = a + F_; row0 = gr - M_; isH2 = true;  }
    int fbase = w * 32;
    vf4 acc[2] = {};
    const float* xp = X + (size_t)(row0 + lr) * FIN_ + lg * 8;
#pragma unroll
    for (int kk = 0; kk < FIN_; kk += 32) {
        float4 xa = *(const float4*)(xp + kk);
        float4 xb = *(const float4*)(xp + kk + 4);
        ABu af;
        af.s[0] = (short)f2b(xa.x); af.s[1] = (short)f2b(xa.y);
        af.s[2] = (short)f2b(xa.z); af.s[3] = (short)f2b(xa.w);
        af.s[4] = (short)f2b(xb.x); af.s[5] = (short)f2b(xb.y);
        af.s[6] = (short)f2b(xb.z); af.s[7] = (short)f2b(xb.w);
#pragma unroll
        for (int q = 0; q < 2; ++q) {
            ABu bf; bf.s = *(const vs8*)(WT + (fbase + q * 16 + lr) * FIN_ + kk + lg * 8);
            acc[q] = mfma16(af, bf, acc[q]);
        }
    }
    // h2 f32 (needed by the h2wP gather); h1 f32 never consumed -> skip
    if (isH2) {
#pragma unroll
        for (int q = 0; q < 2; ++q)
#pragma unroll
            for (int r = 0; r < 4; ++r)
                h2[(size_t)(row0 + lg * 4 + r) * F_ + fbase + q * 16 + lr] = acc[q][r];
    }
    // stage bf16 tile for packed HP write
#pragma unroll
    for (int q = 0; q < 2; ++q)
#pragma unroll
        for (int r = 0; r < 4; ++r)
            tb[lg * 4 + r][fbase + q * 16 + lr] = f2b(acc[q][r]);
    // s row-dot
    float a0 = av[fbase + lr], a1 = av[fbase + 16 + lr];
    float tv[4];
#pragma unroll
    for (int r = 0; r < 4; ++r) tv[r] = acc[0][r] * a0 + acc[1][r] * a1;
#pragma unroll
    for (int off = 1; off < 16; off <<= 1)
#pragma unroll
        for (int r = 0; r < 4; ++r) tv[r] += __shfl_xor(tv[r], off, 64);
    if ((l & 15) == 0)
#pragma unroll
        for (int r = 0; r < 4; ++r) sred[w][lg * 4 + r] = tv[r];
    __syncthreads();
    // HP[row0>>5][f][(row0&16) + half*8 + j] ; 2 threads per f
    {
        int f = t >> 1, half = t & 1;
        vs8 o;
#pragma unroll
        for (int j = 0; j < 8; ++j) o[j] = (short)tb[half * 8 + j][f];
        *(vs8*)(HP + ((size_t)(row0 >> 5) * 128 + f) * 32 + (row0 & 16) + half * 8) = o;
    }
    if (t < 16) {
        float s = sred[0][t] + sred[1][t] + sred[2][t] + sred[3][t];
        sout[row0 + t] = s;
    }
}

// ---- FUSED: inter stats+bitmask | city/prov bitmask+counts | h2wP gather ----
__global__ __launch_bounds__(256) void k_adjgather(const int* __restrict__ inter, const float* __restrict__ s1,
                                                   const float* __restrict__ s2, unsigned short* __restrict__ bm,
                                                   float* __restrict__ rowmax, float* __restrict__ rowinv,
                                                   const int* __restrict__ city, const int* __restrict__ prov,
                                                   const int* __restrict__ src,
                                                   uint32_t* __restrict__ BMtc, uint32_t* __restrict__ BMtp,
                                                   float* __restrict__ w3, float* __restrict__ w4,
                                                   const float* __restrict__ h2, unsigned short* __restrict__ h2wP) {
    __shared__ float wred[8];
    int t = threadIdx.x;
    int wv = t >> 6, ln = t & 63;
    if (blockIdx.x < N_) {
        // ---- inter_adj row stats + bitmask ----
        int n = blockIdx.x;
        const int* rp = inter + (size_t)n * M_ + t * 16;
        float sv[16]; unsigned mask = 0;
#pragma unroll
        for (int c = 0; c < 4; ++c) {
            int4 v = *(const int4*)(rp + c * 4);
            if (v.x > 0) mask |= 1u << (c * 4 + 0);
            if (v.y > 0) mask |= 1u << (c * 4 + 1);
            if (v.z > 0) mask |= 1u << (c * 4 + 2);
            if (v.w > 0) mask |= 1u << (c * 4 + 3);
            float4 s = *(const float4*)(s1 + t * 16 + c * 4);
            sv[c * 4 + 0] = s.x; sv[c * 4 + 1] = s.y; sv[c * 4 + 2] = s.z; sv[c * 4 + 3] = s.w;
        }
        bm[(size_t)n * 256 + t] = (unsigned short)(mask & 0xffffu);
        float mx = -3.0e38f;
#pragma unroll
        for (int j = 0; j < 16; ++j) if (mask & (1u << j)) mx = fmaxf(mx, sv[j]);
        for (int off = 32; off > 0; off >>= 1) mx = fmaxf(mx, __shfl_down(mx, off, 64));
        if (ln == 0) wred[wv] = mx;
        __syncthreads();
        float s1mx = fmaxf(fmaxf(wred[0], wred[1]), fmaxf(wred[2], wred[3]));
        float s2n = s2[n];
        float rmx = lrelu(s2n + s1mx);
        float sum = 0.f;
#pragma unroll
        for (int j = 0; j < 16; ++j) if (mask & (1u << j)) sum += __expf(lrelu(s2n + sv[j]) - rmx);
        for (int off = 32; off > 0; off >>= 1) sum += __shfl_down(sum, off, 64);
        if (ln == 0) wred[4 + wv] = sum;
        __syncthreads();
        if (t == 0) {
            float tot = wred[4] + wred[5] + wred[6] + wred[7];
            bool any = s1mx > -2.9e38f;
            rowmax[n] = any ? rmx : 0.f;
            rowinv[n] = (any && tot > 0.f) ? 1.0f / tot : 0.f;
        }
    } else if (blockIdx.x < N_ + 2 * B_) {
        // ---- city/prov transposed bitmask + counts ----
        int bb = blockIdx.x - N_;
        int b = bb & (B_ - 1);
        bool isC = bb < B_;
        const int* adj = isC ? city : prov;
        uint32_t* BM = isC ? BMtc : BMtp;
        float* wout = isC ? w3 : w4;
        const int* rowp = adj + (size_t)src[b] * N_;
        int cnt = 0;
#pragma unroll 4
        for (int i = 0; i < N_ / 256; ++i) {
            int v = rowp[i * 256 + t];
            unsigned long long bal = __ballot(v > 0);
            cnt += (v > 0);
            if (ln == 0) {
                int widx = i * 8 + wv * 2;
                BM[(size_t)widx * B_ + b] = (uint32_t)bal;
                BM[(size_t)(widx + 1) * B_ + b] = (uint32_t)(bal >> 32);
            }
        }
        float fc = (float)cnt;
        for (int off = 32; off > 0; off >>= 1) fc += __shfl_down(fc, off, 64);
        if (ln == 0) wred[wv] = fc;
        __syncthreads();
        if (t == 0) {
            float tot = wred[0] + wred[1] + wred[2] + wred[3];
            wout[b] = tot > 0.f ? 1.0f / tot : 0.f;
        }
    } else {
        // ---- h2wP gather: h2wP[bblk][f][k'] = bf16(h2[src[bblk*32+k']][f]) ----
        int bblk = blockIdx.x - (N_ + 2 * B_);            // 64 blocks
        int f = t & 127, halfb = t >> 7;
        vs8 o0, o1;
#pragma unroll
        for (int i = 0; i < 8; ++i) {
            int b0 = bblk * 32 + halfb * 16 + i;
            o0[i] = (short)f2b(h2[(size_t)src[b0] * F_ + f]);
            int b1 = b0 + 8;
            o1[i] = (short)f2b(h2[(size_t)src[b1] * F_ + f]);
        }
        unsigned short* dst = h2wP + ((size_t)bblk * 128 + f) * 32 + halfb * 16;
        *(vs8*)dst = o0;
        *(vs8*)(dst + 8) = o1;
    }
}

// ---- materialize att in packed layout attP[mblk][n][k'] (k'=m&31), coalesced 16B/lane ----
__global__ __launch_bounds__(256) void k_attmat(const unsigned char* __restrict__ bm8,
                                                const float* __restrict__ s1, const float* __restrict__ s2,
                                                const float* __restrict__ rowmax, const float* __restrict__ rowinv,
                                                unsigned short* __restrict__ attP) {
    int tid = blockIdx.x * 256 + threadIdx.x;            // 4,194,304 threads
    int moct = tid & 3;
    int n = (tid >> 2) & (N_ - 1);
    int mblk = tid >> 15;
    int m = mblk * 32 + moct * 8;
    unsigned bits = bm8[(size_t)n * 512 + (m >> 3)];
    float s2n = s2[n], rmx = rowmax[n], rin = rowinv[n];
    float4 sa = *(const float4*)(s1 + m);
    float4 sb = *(const float4*)(s1 + m + 4);
    float sv[8] = {sa.x, sa.y, sa.z, sa.w, sb.x, sb.y, sb.z, sb.w};
    vs8 o;
#pragma unroll
    for (int j = 0; j < 8; ++j) {
        float v = (bits & (1u << j)) ? __expf(lrelu(s2n + sv[j]) - rmx) * rin : 0.f;
        o[j] = (short)f2b(v);
    }
    *(vs8*)(attP + ((size_t)mblk * N_ + n) * 32 + moct * 8) = o;
}

// ---- MERGED gemmA | gemmB | gemmC, all operands fragment-packed (dense 1KB/wave loads) ----
__global__ __launch_bounds__(256) void k_gemmABC(const unsigned short* __restrict__ attP,
                                                 const unsigned short* __restrict__ h1P,
                                                 const unsigned short* __restrict__ h2P,
                                                 const uint32_t* __restrict__ BMtc, const uint32_t* __restrict__ BMtp,
                                                 const float* __restrict__ w3, const float* __restrict__ w4,
                                                 const unsigned short* __restrict__ h2wP,
                                                 float* __restrict__ u_in, float* __restrict__ v_in) {
    __shared__ unsigned short lds[32][34];
    int t = threadIdx.x;
    int w = t >> 6, l = t & 63;
    int lr = l & 15, lg = l >> 4;
    int bx = blockIdx.x;
    if (bx < 1024) {
        // ---- gemmA: u_in += att @ h1 (K-slice M/4) ----
        int xa = bx & 255, ya = bx >> 8;
        int nb = xa * 32 + (w >> 1) * 16;
        int fb = (w & 1) * 64;
        vf4 acc[4] = {};
        for (int mblk = ya * 32; mblk < ya * 32 + 32; ++mblk) {
            ABu af; af.s = *(const vs8*)(attP + ((size_t)mblk * N_ + nb + lr) * 32 + lg * 8);
#pragma unroll
            for (int q = 0; q < 4; ++q) {
                ABu bf; bf.s = *(const vs8*)(h1P + ((size_t)mblk * 128 + fb + q * 16 + lr) * 32 + lg * 8);
                acc[q] = mfma16(af, bf, acc[q]);
            }
        }
#pragma unroll
        for (int q = 0; q < 4; ++q)
#pragma unroll
            for (int r = 0; r < 4; ++r)
                atomicAdd(&u_in[(size_t)(nb + lg * 4 + r) * F_ + fb + q * 16 + lr], acc[q][r]);
    } else if (bx < 1536) {
        // ---- gemmB: v_in += att.T @ h2 via LDS transpose (K-slice N/4) ----
        int i = bx - 1024;
        int xb = i & 127, yb = i >> 7;
        int mb = xb * 32;
        int mh = (w >> 1) * 16;
        int fb = (w & 1) * 64;
        int si = t >> 3;
        int sc = (t & 7) * 4;
        vf4 acc[4] = {};
        const unsigned short* abase = attP + (size_t)(mb >> 5) * N_ * 32;
        int n0s = yb * (N_ / 4);
        for (int n0 = n0s; n0 < n0s + N_ / 4; n0 += 32) {
            uint2 dv = *(const uint2*)(abase + (size_t)(n0 + si) * 32 + sc);   // 4 m-vals, dense row
            __syncthreads();
            lds[sc + 0][si] = (unsigned short)(dv.x & 0xffffu);
            lds[sc + 1][si] = (unsigned short)(dv.x >> 16);
            lds[sc + 2][si] = (unsigned short)(dv.y & 0xffffu);
            lds[sc + 3][si] = (unsigned short)(dv.y >> 16);
            __syncthreads();
            ABu af; af.s = *(const vs8*)&lds[mh + lr][lg * 8];
#pragma unroll
            for (int q = 0; q < 4; ++q) {
                ABu bf; bf.s = *(const vs8*)(h2P + ((size_t)(n0 >> 5) * 128 + fb + q * 16 + lr) * 32 + lg * 8);
                acc[q] = mfma16(af, bf, acc[q]);
            }
        }
#pragma unroll
        for (int q = 0; q < 4; ++q)
#pragma unroll
            for (int r = 0; r < 4; ++r)
                atomicAdd(&v_in[(size_t)(mb + mh + lg * 4 + r) * F_ + fb + q * 16 + lr], acc[q][r]);
    } else {
        // ---- gemmC: u_in += G @ h2w, G on-the-fly from transposed bitmasks (K-slice B/2) ----
        int i = bx - 1536;
        int xc = i & 255, yc = i >> 8;
        int nb = xc * 32 + (w >> 1) * 16;
        int fb = (w & 1) * 64;
        int n = nb + lr;
        int wi = n >> 5;
        int bitpos = n & 31;
        const uint32_t* bc = BMtc + (size_t)wi * B_;
        const uint32_t* bp = BMtp + (size_t)wi * B_;
        vf4 acc[4] = {};
        int b0s = yc * (B_ / 2);
        for (int b0 = b0s; b0 < b0s + B_ / 2; b0 += 32) {
            int bb = b0 + lg * 8;
            uint4 c0 = *(const uint4*)(bc + bb);
            uint4 c1 = *(const uint4*)(bc + bb + 4);
            uint4 p0 = *(const uint4*)(bp + bb);
            uint4 p1 = *(const uint4*)(bp + bb + 4);
            float4 wa = *(const float4*)(w3 + bb);
            float4 wb = *(const float4*)(w3 + bb + 4);
            float4 wc = *(const float4*)(w4 + bb);
            float4 wd = *(const float4*)(w4 + bb + 4);
            uint32_t cw[8] = {c0.x, c0.y, c0.z, c0.w, c1.x, c1.y, c1.z, c1.w};
            uint32_t pw[8] = {p0.x, p0.y, p0.z, p0.w, p1.x, p1.y, p1.z, p1.w};
            float w3v[8] = {wa.x, wa.y, wa.z, wa.w, wb.x, wb.y, wb.z, wb.w};
            float w4v[8] = {wc.x, wc.y, wc.z, wc.w, wd.x, wd.y, wd.z, wd.w};
            ABu af;
#pragma unroll
            for (int j = 0; j < 8; ++j) {
                float v = (((cw[j] >> bitpos) & 1u) ? w3v[j] : 0.f) + (((pw[j] >> bitpos) & 1u) ? w4v[j] : 0.f);
                af.s[j] = (short)f2b(v);
            }
#pragma unroll
            for (int q = 0; q < 4; ++q) {
                ABu bf; bf.s = *(const vs8*)(h2wP + ((size_t)(b0 >> 5) * 128 + fb + q * 16 + lr) * 32 + lg * 8);
                acc[q] = mfma16(af, bf, acc[q]);
            }
        }
#pragma unroll
        for (int q = 0; q < 4; ++q)
#pragma unroll
            for (int r = 0; r < 4; ++r)
                atomicAdd(&u_in[(size_t)(nb + lg * 4 + r) * F_ + fb + q * 16 + lr], acc[q][r]);
    }
}

// ---------------- batchnorm column stats, both matrices in one launch ----------------
__global__ __launch_bounds__(256) void k_bnstats2(const float* __restrict__ v_in, const float* __restrict__ u_in,
                                                  float* __restrict__ stats) {
    __shared__ float r1[256], r2[256];
    int bx = blockIdx.x;
    const float* P; int R; float* sum; float* sq;
    if (bx < 128) { P = v_in; R = M_; sum = stats;       sq = stats + 128; }
    else          { P = u_in; R = N_; sum = stats + 256; sq = stats + 384; bx -= 128; }
    int f = threadIdx.x & 127;
    int half = threadIdx.x >> 7;
    float s = 0.f, s2v = 0.f;
    for (int r = bx * 2 + half; r < R; r += 256) {
        float v = P[(size_t)r * F_ + f];
        s += v; s2v += v * v;
    }
    r1[threadIdx.x] = s; r2[threadIdx.x] = s2v;
    __syncthreads();
    if (half == 0) {
        atomicAdd(&sum[f], r1[f] + r1[f + 128]);
        atomicAdd(&sq[f], r2[f] + r2[f + 128]);
    }
}

// ---- bn finalize (per-block recompute) + apply + leaky + cast bf16, float4-vectorized ----
__global__ __launch_bounds__(256) void k_bnapplyF(const float* __restrict__ v_in, const float* __restrict__ u_in,
                                                  const float* __restrict__ stats,
                                                  const float* __restrict__ g1, const float* __restrict__ b1,
                                                  const float* __restrict__ g2, const float* __restrict__ b2,
                                                  unsigned short* __restrict__ v_outb, unsigned short* __restrict__ u_outb) {
    __shared__ float sc[256], sh[256];                    // [which*128+f]
    int t = threadIdx.x;
    {
        int which = t >> 7, f = t & 127;
        const float* sum = stats + which * 256;
        const float* sq = sum + 128;
        const float* g = which ? g2 : g1;
        const float* be = which ? b2 : b1;
        float R = which ? (float)N_ : (float)M_;
        float mean = sum[f] / R;
        float var = sq[f] / R - mean * mean;
        float s = g[f] * rsqrtf(var + 1e-5f);
        sc[t] = s; sh[t] = be[f] - mean * s;
    }
    __syncthreads();
    int id4 = blockIdx.x * 256 + t;                       // one float4 per thread
    int idx = id4 * 4;
    int which = idx >= M_ * F_;
    int rel = which ? idx - M_ * F_ : idx;
    const float* P = which ? u_in : v_in;
    unsigned short* Q = which ? u_outb : v_outb;
    int f0 = (rel & 127) + which * 128;
    float4 p = *(const float4*)(P + rel);
    ushort4 o;
    o.x = f2b(lrelu(p.x * sc[f0 + 0] + sh[f0 + 0]));
    o.y = f2b(lrelu(p.y * sc[f0 + 1] + sh[f0 + 1]));
    o.z = f2b(lrelu(p.z * sc[f0 + 2] + sh[f0 + 2]));
    o.w = f2b(lrelu(p.w * sc[f0 + 3] + sh[f0 + 3]));
    *(ushort4*)(Q + rel) = o;
}

// ---------------- out = elu(U @ V^T) ----------------
__global__ __launch_bounds__(256) void k_gemmD(const unsigned short* __restrict__ U,
                                               const unsigned short* __restrict__ V,
                                               float* __restrict__ out) {
    int w = threadIdx.x >> 6, l = threadIdx.x & 63;
    int lr = l & 15, lg = l >> 4;
    int nb = blockIdx.x * 64 + w * 16;
    int mb = blockIdx.y * 64;
    vf4 acc[4] = {};
#pragma unroll
    for (int k0 = 0; k0 < F_; k0 += 32) {
        ABu af; af.s = *(const vs8*)(U + (size_t)(nb + lr) * F_ + k0 + lg * 8);
#pragma unroll
        for (int q = 0; q < 4; ++q) {
            ABu bf; bf.s = *(const vs8*)(V + (size_t)(mb + q * 16 + lr) * F_ + k0 + lg * 8);
            acc[q] = mfma16(af, bf, acc[q]);
        }
    }
#pragma unroll
    for (int q = 0; q < 4; ++q)
#pragma unroll
        for (int r = 0; r < 4; ++r) {
            int row = nb + lg * 4 + r;
            int col = mb + q * 16 + lr;
            float x = acc[q][r];
            out[(size_t)row * M_ + col] = x > 0.f ? x : __expf(x) - 1.f;
        }
}

extern "C" void kernel_launch(void* const* d_in, const int* in_sizes, int n_in,
                              void* d_out, int out_size, void* d_ws, size_t ws_size,
                              hipStream_t stream) {
    const float* Sinput = (const float*)d_in[0];
    const float* Rinput = (const float*)d_in[1];
    const int* inter_adj = (const int*)d_in[2];
    const int* city_adj = (const int*)d_in[3];
    const int* prov_adj = (const int*)d_in[4];
    const int* src = (const int*)d_in[5];
    const float* W1 = (const float*)d_in[6];
    const float* W2 = (const float*)d_in[7];
    const float* a = (const float*)d_in[8];
    const float* g1 = (const float*)d_in[11];
    const float* b1 = (const float*)d_in[12];
    const float* g2 = (const float*)d_in[13];
    const float* b2 = (const float*)d_in[14];
    float* out = (float*)d_out;

    char* ws = (char*)d_ws;
    size_t o = 0;
    auto take = [&](size_t bytes) { char* p = ws + o; o += (bytes + 255) & ~(size_t)255; return p; };
    float* u_in = (float*)take((size_t)N_ * F_ * 4);
    float* v_in = (float*)take((size_t)M_ * F_ * 4);
    float* stats = (float*)take(512 * 4);
    size_t zero_bytes = o;                               // u_in + v_in + stats zeroed each launch
    float* h2 = (float*)take((size_t)N_ * F_ * 4);
    unsigned short* h1P = (unsigned short*)take((size_t)(M_ / 32) * 128 * 32 * 2);
    unsigned short* h2P = (unsigned short*)take((size_t)(N_ / 32) * 128 * 32 * 2);
    unsigned short* W1T = (unsigned short*)take((size_t)F_ * FIN_ * 2);
    unsigned short* W2T = (unsigned short*)take((size_t)F_ * FIN_ * 2);
    float* s1 = (float*)take(M_ * 4);
    float* s2 = (float*)take(N_ * 4);
    float* rowmax = (float*)take(N_ * 4);
    float* rowinv = (float*)take(N_ * 4);
    float* w3 = (float*)take(B_ * 4);
    float* w4 = (float*)take(B_ * 4);
    unsigned short* h2wP = (unsigned short*)take((size_t)(B_ / 32) * 128 * 32 * 2);
    unsigned short* u_outb = (unsigned short*)take((size_t)N_ * F_ * 2);
    unsigned short* v_outb = (unsigned short*)take((size_t)M_ * F_ * 2);
    uint32_t* BMtc = (uint32_t*)take((size_t)256 * B_ * 4);
    uint32_t* BMtp = (uint32_t*)take((size_t)256 * B_ * 4);
    unsigned short* bm = (unsigned short*)take((size_t)N_ * 256 * 2);      // 4 MB, [n][m-bits]
    unsigned short* attP = (unsigned short*)take((size_t)N_ * M_ * 2);     // 64 MB packed
    (void)ws_size; (void)in_sizes; (void)n_in; (void)out_size;

    hipMemsetAsync(d_ws, 0, zero_bytes, stream);

    k_wprep<<<256, 256, 0, stream>>>(W1, W2, W1T, W2T);
    k_hgemmF<<<(M_ + N_) / 16, 256, 0, stream>>>(Rinput, Sinput, W1T, W2T, a, h2, h1P, h2P, s1, s2);
    k_adjgather<<<N_ + 2 * B_ + B_ / 32, 256, 0, stream>>>(inter_adj, s1, s2, bm, rowmax, rowinv,
                                                           city_adj, prov_adj, src, BMtc, BMtp, w3, w4,
                                                           h2, h2wP);
    k_attmat<<<16384, 256, 0, stream>>>((const unsigned char*)bm, s1, s2, rowmax, rowinv, attP);
    k_gemmABC<<<2048, 256, 0, stream>>>(attP, h1P, h2P, BMtc, BMtp, w3, w4, h2wP, u_in, v_in);
    k_bnstats2<<<256, 256, 0, stream>>>(v_in, u_in, stats);
    k_bnapplyF<<<(M_ + N_) * F_ / 4 / 256, 256, 0, stream>>>(v_in, u_in, stats, g1, b1, g2, b2, v_outb, u_outb);
    k_gemmD<<<dim3(N_ / 64, M_ / 64), 256, 0, stream>>>(u_outb, v_outb, out);
}

// Round 8
// 352.126 us; speedup vs baseline: 1.4338x; 1.0055x over previous
//
#include <hip/hip_runtime.h>
#include <stdint.h>

#define N_ 8192
#define M_ 4096
#define FIN_ 256
#define F_ 128
#define B_ 2048

typedef __attribute__((ext_vector_type(8))) short vs8;
typedef __attribute__((ext_vector_type(8))) __bf16 vb8;
typedef __attribute__((ext_vector_type(4))) float vf4;

union ABu { vs8 s; vb8 b; };

__device__ __forceinline__ vf4 mfma16(const ABu& a, const ABu& b, vf4 c) {
    return __builtin_amdgcn_mfma_f32_16x16x32_bf16(a.b, b.b, c, 0, 0, 0);
}
__device__ __forceinline__ unsigned short f2b(float x) {
    union { float f; unsigned u; } v; v.f = x;
    unsigned r = v.u + 0x7fffu + ((v.u >> 16) & 1u);
    return (unsigned short)(r >> 16);
}
__device__ __forceinline__ float lrelu(float x) { return x > 0.f ? x : 0.2f * x; }

// ---- prep: W[256][128] f32 -> WT[128][256] bf16  +  zero u_in/v_in/stats (replaces memset) ----
__global__ void k_prep(const float* __restrict__ W1, const float* __restrict__ W2,
                       unsigned short* __restrict__ W1T, unsigned short* __restrict__ W2T,
                       float4* __restrict__ Z, int nz4) {
    int id = blockIdx.x * 256 + threadIdx.x;
    if (id < 65536) {
        const float* W = (id < 32768) ? W1 : W2;
        unsigned short* WT = (id < 32768) ? W1T : W2T;
        int o = id & 32767;
        int f = o >> 8, k = o & 255;
        WT[o] = f2b(W[k * F_ + f]);
    } else {
        int z = id - 65536;
        if (z < nz4) Z[z] = make_float4(0.f, 0.f, 0.f, 0.f);
    }
}

// ---- FUSED: h = X@W (MFMA); write h2 f32, packed hP[kblk][f][32] bf16, s1/s2 row-dots ----
__global__ __launch_bounds__(256) void k_hgemmF(const float* __restrict__ Rin, const float* __restrict__ Sin,
                                                const unsigned short* __restrict__ W1T,
                                                const unsigned short* __restrict__ W2T,
                                                const float* __restrict__ a,
                                                float* __restrict__ h2,
                                                unsigned short* __restrict__ h1P, unsigned short* __restrict__ h2P,
                                                float* __restrict__ s1, float* __restrict__ s2) {
    __shared__ unsigned short tb[16][136];               // 16 rows x 128 f, padded
    __shared__ float sred[4][16];
    int t = threadIdx.x;
    int w = t >> 6, l = t & 63, lr = l & 15, lg = l >> 4;
    int gr = blockIdx.x * 16;
    const float* X; const unsigned short* WT; unsigned short* HP; float* sout; const float* av;
    int row0; bool isH2;
    if (gr < M_) { X = Rin; WT = W1T; HP = h1P; sout = s1; av = a;      row0 = gr;      isH2 = false; }
    else         { X = Sin; WT = W2T; HP = h2P; sout = s2; av = a + F_; row0 = gr - M_; isH2 = true;  }
    int fbase = w * 32;
    vf4 acc[2] = {};
    const float* xp = X + (size_t)(row0 + lr) * FIN_ + lg * 8;
#pragma unroll
    for (int kk = 0; kk < FIN_; kk += 32) {
        float4 xa = *(const float4*)(xp + kk);
        float4 xb = *(const float4*)(xp + kk + 4);
        ABu af;
        af.s[0] = (short)f2b(xa.x); af.s[1] = (short)f2b(xa.y);
        af.s[2] = (short)f2b(xa.z); af.s[3] = (short)f2b(xa.w);
        af.s[4] = (short)f2b(xb.x); af.s[5] = (short)f2b(xb.y);
        af.s[6] = (short)f2b(xb.z); af.s[7] = (short)f2b(xb.w);
#pragma unroll
        for (int q = 0; q < 2; ++q) {
            ABu bf; bf.s = *(const vs8*)(WT + (fbase + q * 16 + lr) * FIN_ + kk + lg * 8);
            acc[q] = mfma16(af, bf, acc[q]);
        }
    }
    if (isH2) {
#pragma unroll
        for (int q = 0; q < 2; ++q)
#pragma unroll
            for (int r = 0; r < 4; ++r)
                h2[(size_t)(row0 + lg * 4 + r) * F_ + fbase + q * 16 + lr] = acc[q][r];
    }
#pragma unroll
    for (int q = 0; q < 2; ++q)
#pragma unroll
        for (int r = 0; r < 4; ++r)
            tb[lg * 4 + r][fbase + q * 16 + lr] = f2b(acc[q][r]);
    float a0 = av[fbase + lr], a1 = av[fbase + 16 + lr];
    float tv[4];
#pragma unroll
    for (int r = 0; r < 4; ++r) tv[r] = acc[0][r] * a0 + acc[1][r] * a1;
#pragma unroll
    for (int off = 1; off < 16; off <<= 1)
#pragma unroll
        for (int r = 0; r < 4; ++r) tv[r] += __shfl_xor(tv[r], off, 64);
    if ((l & 15) == 0)
#pragma unroll
        for (int r = 0; r < 4; ++r) sred[w][lg * 4 + r] = tv[r];
    __syncthreads();
    {
        int f = t >> 1, half = t & 1;
        vs8 o;
#pragma unroll
        for (int j = 0; j < 8; ++j) o[j] = (short)tb[half * 8 + j][f];
        *(vs8*)(HP + ((size_t)(row0 >> 5) * 128 + f) * 32 + (row0 & 16) + half * 8) = o;
    }
    if (t < 16) {
        float s = sred[0][t] + sred[1][t] + sred[2][t] + sred[3][t];
        sout[row0 + t] = s;
    }
}

// ---- FUSED: inter stats+bitmask | city/prov bitmask+counts | h2wP gather ----
__global__ __launch_bounds__(256) void k_adjgather(const int* __restrict__ inter, const float* __restrict__ s1,
                                                   const float* __restrict__ s2, unsigned short* __restrict__ bm,
                                                   float* __restrict__ rowmax, float* __restrict__ rowinv,
                                                   const int* __restrict__ city, const int* __restrict__ prov,
                                                   const int* __restrict__ src,
                                                   uint32_t* __restrict__ BMtc, uint32_t* __restrict__ BMtp,
                                                   float* __restrict__ w3, float* __restrict__ w4,
                                                   const float* __restrict__ h2, unsigned short* __restrict__ h2wP) {
    __shared__ float wred[8];
    int t = threadIdx.x;
    int wv = t >> 6, ln = t & 63;
    if (blockIdx.x < N_) {
        int n = blockIdx.x;
        const int* rp = inter + (size_t)n * M_ + t * 16;
        float sv[16]; unsigned mask = 0;
#pragma unroll
        for (int c = 0; c < 4; ++c) {
            int4 v = *(const int4*)(rp + c * 4);
            if (v.x > 0) mask |= 1u << (c * 4 + 0);
            if (v.y > 0) mask |= 1u << (c * 4 + 1);
            if (v.z > 0) mask |= 1u << (c * 4 + 2);
            if (v.w > 0) mask |= 1u << (c * 4 + 3);
            float4 s = *(const float4*)(s1 + t * 16 + c * 4);
            sv[c * 4 + 0] = s.x; sv[c * 4 + 1] = s.y; sv[c * 4 + 2] = s.z; sv[c * 4 + 3] = s.w;
        }
        bm[(size_t)n * 256 + t] = (unsigned short)(mask & 0xffffu);
        float mx = -3.0e38f;
#pragma unroll
        for (int j = 0; j < 16; ++j) if (mask & (1u << j)) mx = fmaxf(mx, sv[j]);
        for (int off = 32; off > 0; off >>= 1) mx = fmaxf(mx, __shfl_down(mx, off, 64));
        if (ln == 0) wred[wv] = mx;
        __syncthreads();
        float s1mx = fmaxf(fmaxf(wred[0], wred[1]), fmaxf(wred[2], wred[3]));
        float s2n = s2[n];
        float rmx = lrelu(s2n + s1mx);
        float sum = 0.f;
#pragma unroll
        for (int j = 0; j < 16; ++j) if (mask & (1u << j)) sum += __expf(lrelu(s2n + sv[j]) - rmx);
        for (int off = 32; off > 0; off >>= 1) sum += __shfl_down(sum, off, 64);
        if (ln == 0) wred[4 + wv] = sum;
        __syncthreads();
        if (t == 0) {
            float tot = wred[4] + wred[5] + wred[6] + wred[7];
            bool any = s1mx > -2.9e38f;
            rowmax[n] = any ? rmx : 0.f;
            rowinv[n] = (any && tot > 0.f) ? 1.0f / tot : 0.f;
        }
    } else if (blockIdx.x < N_ + 2 * B_) {
        int bb = blockIdx.x - N_;
        int b = bb & (B_ - 1);
        bool isC = bb < B_;
        const int* adj = isC ? city : prov;
        uint32_t* BM = isC ? BMtc : BMtp;
        float* wout = isC ? w3 : w4;
        const int* rowp = adj + (size_t)src[b] * N_;
        int cnt = 0;
#pragma unroll 4
        for (int i = 0; i < N_ / 256; ++i) {
            int v = rowp[i * 256 + t];
            unsigned long long bal = __ballot(v > 0);
            cnt += (v > 0);
            if (ln == 0) {
                int widx = i * 8 + wv * 2;
                BM[(size_t)widx * B_ + b] = (uint32_t)bal;
                BM[(size_t)(widx + 1) * B_ + b] = (uint32_t)(bal >> 32);
            }
        }
        float fc = (float)cnt;
        for (int off = 32; off > 0; off >>= 1) fc += __shfl_down(fc, off, 64);
        if (ln == 0) wred[wv] = fc;
        __syncthreads();
        if (t == 0) {
            float tot = wred[0] + wred[1] + wred[2] + wred[3];
            wout[b] = tot > 0.f ? 1.0f / tot : 0.f;
        }
    } else {
        int bblk = blockIdx.x - (N_ + 2 * B_);            // 64 blocks
        int f = t & 127, halfb = t >> 7;
        vs8 o0, o1;
#pragma unroll
        for (int i = 0; i < 8; ++i) {
            int b0 = bblk * 32 + halfb * 16 + i;
            o0[i] = (short)f2b(h2[(size_t)src[b0] * F_ + f]);
            int b1 = b0 + 8;
            o1[i] = (short)f2b(h2[(size_t)src[b1] * F_ + f]);
        }
        unsigned short* dst = h2wP + ((size_t)bblk * 128 + f) * 32 + halfb * 16;
        *(vs8*)dst = o0;
        *(vs8*)(dst + 8) = o1;
    }
}

// ---- materialize att in packed layout attP[mblk][n][k'] (k'=m&31), coalesced 16B/lane ----
__global__ __launch_bounds__(256) void k_attmat(const unsigned char* __restrict__ bm8,
                                                const float* __restrict__ s1, const float* __restrict__ s2,
                                                const float* __restrict__ rowmax, const float* __restrict__ rowinv,
                                                unsigned short* __restrict__ attP) {
    int tid = blockIdx.x * 256 + threadIdx.x;            // 4,194,304 threads
    int moct = tid & 3;
    int n = (tid >> 2) & (N_ - 1);
    int mblk = tid >> 15;
    int m = mblk * 32 + moct * 8;
    unsigned bits = bm8[(size_t)n * 512 + (m >> 3)];
    float s2n = s2[n], rmx = rowmax[n], rin = rowinv[n];
    float4 sa = *(const float4*)(s1 + m);
    float4 sb = *(const float4*)(s1 + m + 4);
    float sv[8] = {sa.x, sa.y, sa.z, sa.w, sb.x, sb.y, sb.z, sb.w};
    vs8 o;
#pragma unroll
    for (int j = 0; j < 8; ++j) {
        float v = (bits & (1u << j)) ? __expf(lrelu(s2n + sv[j]) - rmx) * rin : 0.f;
        o[j] = (short)f2b(v);
    }
    *(vs8*)(attP + ((size_t)mblk * N_ + n) * 32 + moct * 8) = o;
}

// ---- MERGED gemmA | gemmB | gemmC, all operands fragment-packed (dense 1KB/wave loads) ----
__global__ __launch_bounds__(256) void k_gemmABC(const unsigned short* __restrict__ attP,
                                                 const unsigned short* __restrict__ h1P,
                                                 const unsigned short* __restrict__ h2P,
                                                 const uint32_t* __restrict__ BMtc, const uint32_t* __restrict__ BMtp,
                                                 const float* __restrict__ w3, const float* __restrict__ w4,
                                                 const unsigned short* __restrict__ h2wP,
                                                 float* __restrict__ u_in, float* __restrict__ v_in) {
    __shared__ unsigned short lds[32][34];
    int t = threadIdx.x;
    int w = t >> 6, l = t & 63;
    int lr = l & 15, lg = l >> 4;
    int bx = blockIdx.x;
    if (bx < 1024) {
        int xa = bx & 255, ya = bx >> 8;
        int nb = xa * 32 + (w >> 1) * 16;
        int fb = (w & 1) * 64;
        vf4 acc[4] = {};
        for (int mblk = ya * 32; mblk < ya * 32 + 32; ++mblk) {
            ABu af; af.s = *(const vs8*)(attP + ((size_t)mblk * N_ + nb + lr) * 32 + lg * 8);
#pragma unroll
            for (int q = 0; q < 4; ++q) {
                ABu bf; bf.s = *(const vs8*)(h1P + ((size_t)mblk * 128 + fb + q * 16 + lr) * 32 + lg * 8);
                acc[q] = mfma16(af, bf, acc[q]);
            }
        }
#pragma unroll
        for (int q = 0; q < 4; ++q)
#pragma unroll
            for (int r = 0; r < 4; ++r)
                atomicAdd(&u_in[(size_t)(nb + lg * 4 + r) * F_ + fb + q * 16 + lr], acc[q][r]);
    } else if (bx < 1536) {
        int i = bx - 1024;
        int xb = i & 127, yb = i >> 7;
        int mb = xb * 32;
        int mh = (w >> 1) * 16;
        int fb = (w & 1) * 64;
        int si = t >> 3;
        int sc = (t & 7) * 4;
        vf4 acc[4] = {};
        const unsigned short* abase = attP + (size_t)(mb >> 5) * N_ * 32;
        int n0s = yb * (N_ / 4);
        for (int n0 = n0s; n0 < n0s + N_ / 4; n0 += 32) {
            uint2 dv = *(const uint2*)(abase + (size_t)(n0 + si) * 32 + sc);
            __syncthreads();
            lds[sc + 0][si] = (unsigned short)(dv.x & 0xffffu);
            lds[sc + 1][si] = (unsigned short)(dv.x >> 16);
            lds[sc + 2][si] = (unsigned short)(dv.y & 0xffffu);
            lds[sc + 3][si] = (unsigned short)(dv.y >> 16);
            __syncthreads();
            ABu af; af.s = *(const vs8*)&lds[mh + lr][lg * 8];
#pragma unroll
            for (int q = 0; q < 4; ++q) {
                ABu bf; bf.s = *(const vs8*)(h2P + ((size_t)(n0 >> 5) * 128 + fb + q * 16 + lr) * 32 + lg * 8);
                acc[q] = mfma16(af, bf, acc[q]);
            }
        }
#pragma unroll
        for (int q = 0; q < 4; ++q)
#pragma unroll
            for (int r = 0; r < 4; ++r)
                atomicAdd(&v_in[(size_t)(mb + mh + lg * 4 + r) * F_ + fb + q * 16 + lr], acc[q][r]);
    } else {
        int i = bx - 1536;
        int xc = i & 255, yc = i >> 8;
        int nb = xc * 32 + (w >> 1) * 16;
        int fb = (w & 1) * 64;
        int n = nb + lr;
        int wi = n >> 5;
        int bitpos = n & 31;
        const uint32_t* bc = BMtc + (size_t)wi * B_;
        const uint32_t* bp = BMtp + (size_t)wi * B_;
        vf4 acc[4] = {};
        int b0s = yc * (B_ / 2);
        for (int b0 = b0s; b0 < b0s + B_ / 2; b0 += 32) {
            int bb = b0 + lg * 8;
            uint4 c0 = *(const uint4*)(bc + bb);
            uint4 c1 = *(const uint4*)(bc + bb + 4);
            uint4 p0 = *(const uint4*)(bp + bb);
            uint4 p1 = *(const uint4*)(bp + bb + 4);
            float4 wa = *(const float4*)(w3 + bb);
            float4 wb = *(const float4*)(w3 + bb + 4);
            float4 wc = *(const float4*)(w4 + bb);
            float4 wd = *(const float4*)(w4 + bb + 4);
            uint32_t cw[8] = {c0.x, c0.y, c0.z, c0.w, c1.x, c1.y, c1.z, c1.w};
            uint32_t pw[8] = {p0.x, p0.y, p0.z, p0.w, p1.x, p1.y, p1.z, p1.w};
            float w3v[8] = {wa.x, wa.y, wa.z, wa.w, wb.x, wb.y, wb.z, wb.w};
            float w4v[8] = {wc.x, wc.y, wc.z, wc.w, wd.x, wd.y, wd.z, wd.w};
            ABu af;
#pragma unroll
            for (int j = 0; j < 8; ++j) {
                float v = (((cw[j] >> bitpos) & 1u) ? w3v[j] : 0.f) + (((pw[j] >> bitpos) & 1u) ? w4v[j] : 0.f);
                af.s[j] = (short)f2b(v);
            }
#pragma unroll
            for (int q = 0; q < 4; ++q) {
                ABu bf; bf.s = *(const vs8*)(h2wP + ((size_t)(b0 >> 5) * 128 + fb + q * 16 + lr) * 32 + lg * 8);
                acc[q] = mfma16(af, bf, acc[q]);
            }
        }
#pragma unroll
        for (int q = 0; q < 4; ++q)
#pragma unroll
            for (int r = 0; r < 4; ++r)
                atomicAdd(&u_in[(size_t)(nb + lg * 4 + r) * F_ + fb + q * 16 + lr], acc[q][r]);
    }
}

// ---------------- batchnorm column stats, both matrices in one launch ----------------
__global__ __launch_bounds__(256) void k_bnstats2(const float* __restrict__ v_in, const float* __restrict__ u_in,
                                                  float* __restrict__ stats) {
    __shared__ float r1[256], r2[256];
    int bx = blockIdx.x;
    const float* P; int R; float* sum; float* sq;
    if (bx < 128) { P = v_in; R = M_; sum = stats;       sq = stats + 128; }
    else          { P = u_in; R = N_; sum = stats + 256; sq = stats + 384; bx -= 128; }
    int f = threadIdx.x & 127;
    int half = threadIdx.x >> 7;
    float s = 0.f, s2v = 0.f;
    for (int r = bx * 2 + half; r < R; r += 256) {
        float v = P[(size_t)r * F_ + f];
        s += v; s2v += v * v;
    }
    r1[threadIdx.x] = s; r2[threadIdx.x] = s2v;
    __syncthreads();
    if (half == 0) {
        atomicAdd(&sum[f], r1[f] + r1[f + 128]);
        atomicAdd(&sq[f], r2[f] + r2[f + 128]);
    }
}

// ---- bn finalize (per-block recompute) + apply + leaky + cast bf16, float4-vectorized ----
__global__ __launch_bounds__(256) void k_bnapplyF(const float* __restrict__ v_in, const float* __restrict__ u_in,
                                                  const float* __restrict__ stats,
                                                  const float* __restrict__ g1, const float* __restrict__ b1,
                                                  const float* __restrict__ g2, const float* __restrict__ b2,
                                                  unsigned short* __restrict__ v_outb, unsigned short* __restrict__ u_outb) {
    __shared__ float sc[256], sh[256];                    // [which*128+f]
    int t = threadIdx.x;
    {
        int which = t >> 7, f = t & 127;
        const float* sum = stats + which * 256;
        const float* sq = sum + 128;
        const float* g = which ? g2 : g1;
        const float* be = which ? b2 : b1;
        float R = which ? (float)N_ : (float)M_;
        float mean = sum[f] / R;
        float var = sq[f] / R - mean * mean;
        float s = g[f] * rsqrtf(var + 1e-5f);
        sc[t] = s; sh[t] = be[f] - mean * s;
    }
    __syncthreads();
    int id4 = blockIdx.x * 256 + t;                       // one float4 per thread
    int idx = id4 * 4;
    int which = idx >= M_ * F_;
    int rel = which ? idx - M_ * F_ : idx;
    const float* P = which ? u_in : v_in;
    unsigned short* Q = which ? u_outb : v_outb;
    int f0 = (rel & 127) + which * 128;
    float4 p = *(const float4*)(P + rel);
    ushort4 o;
    o.x = f2b(lrelu(p.x * sc[f0 + 0] + sh[f0 + 0]));
    o.y = f2b(lrelu(p.y * sc[f0 + 1] + sh[f0 + 1]));
    o.z = f2b(lrelu(p.z * sc[f0 + 2] + sh[f0 + 2]));
    o.w = f2b(lrelu(p.w * sc[f0 + 3] + sh[f0 + 3]));
    *(ushort4*)(Q + rel) = o;
}

// ---------------- out = elu(U @ V^T) ----------------
__global__ __launch_bounds__(256) void k_gemmD(const unsigned short* __restrict__ U,
                                               const unsigned short* __restrict__ V,
                                               float* __restrict__ out) {
    int w = threadIdx.x >> 6, l = threadIdx.x & 63;
    int lr = l & 15, lg = l >> 4;
    int nb = blockIdx.x * 64 + w * 16;
    int mb = blockIdx.y * 64;
    vf4 acc[4] = {};
#pragma unroll
    for (int k0 = 0; k0 < F_; k0 += 32) {
        ABu af; af.s = *(const vs8*)(U + (size_t)(nb + lr) * F_ + k0 + lg * 8);
#pragma unroll
        for (int q = 0; q < 4; ++q) {
            ABu bf; bf.s = *(const vs8*)(V + (size_t)(mb + q * 16 + lr) * F_ + k0 + lg * 8);
            acc[q] = mfma16(af, bf, acc[q]);
        }
    }
#pragma unroll
    for (int q = 0; q < 4; ++q)
#pragma unroll
        for (int r = 0; r < 4; ++r) {
            int row = nb + lg * 4 + r;
            int col = mb + q * 16 + lr;
            float x = acc[q][r];
            out[(size_t)row * M_ + col] = x > 0.f ? x : __expf(x) - 1.f;
        }
}

extern "C" void kernel_launch(void* const* d_in, const int* in_sizes, int n_in,
                              void* d_out, int out_size, void* d_ws, size_t ws_size,
                              hipStream_t stream) {
    const float* Sinput = (const float*)d_in[0];
    const float* Rinput = (const float*)d_in[1];
    const int* inter_adj = (const int*)d_in[2];
    const int* city_adj = (const int*)d_in[3];
    const int* prov_adj = (const int*)d_in[4];
    const int* src = (const int*)d_in[5];
    const float* W1 = (const float*)d_in[6];
    const float* W2 = (const float*)d_in[7];
    const float* a = (const float*)d_in[8];
    const float* g1 = (const float*)d_in[11];
    const float* b1 = (const float*)d_in[12];
    const float* g2 = (const float*)d_in[13];
    const float* b2 = (const float*)d_in[14];
    float* out = (float*)d_out;

    char* ws = (char*)d_ws;
    size_t o = 0;
    auto take = [&](size_t bytes) { char* p = ws + o; o += (bytes + 255) & ~(size_t)255; return p; };
    float* u_in = (float*)take((size_t)N_ * F_ * 4);
    float* v_in = (float*)take((size_t)M_ * F_ * 4);
    float* stats = (float*)take(512 * 4);
    size_t zero_bytes = o;                               // u_in + v_in + stats, zeroed by k_prep
    float* h2 = (float*)take((size_t)N_ * F_ * 4);
    unsigned short* h1P = (unsigned short*)take((size_t)(M_ / 32) * 128 * 32 * 2);
    unsigned short* h2P = (unsigned short*)take((size_t)(N_ / 32) * 128 * 32 * 2);
    unsigned short* W1T = (unsigned short*)take((size_t)F_ * FIN_ * 2);
    unsigned short* W2T = (unsigned short*)take((size_t)F_ * FIN_ * 2);
    float* s1 = (float*)take(M_ * 4);
    float* s2 = (float*)take(N_ * 4);
    float* rowmax = (float*)take(N_ * 4);
    float* rowinv = (float*)take(N_ * 4);
    float* w3 = (float*)take(B_ * 4);
    float* w4 = (float*)take(B_ * 4);
    unsigned short* h2wP = (unsigned short*)take((size_t)(B_ / 32) * 128 * 32 * 2);
    unsigned short* u_outb = (unsigned short*)take((size_t)N_ * F_ * 2);
    unsigned short* v_outb = (unsigned short*)take((size_t)M_ * F_ * 2);
    uint32_t* BMtc = (uint32_t*)take((size_t)256 * B_ * 4);
    uint32_t* BMtp = (uint32_t*)take((size_t)256 * B_ * 4);
    unsigned short* bm = (unsigned short*)take((size_t)N_ * 256 * 2);      // 4 MB, [n][m-bits]
    unsigned short* attP = (unsigned short*)take((size_t)N_ * M_ * 2);     // 64 MB packed
    (void)ws_size; (void)in_sizes; (void)n_in; (void)out_size;

    int nz4 = (int)(zero_bytes / 16);                    // zero region as float4s (256-aligned)
    int zblocks = (nz4 + 255) / 256;
    k_prep<<<256 + zblocks, 256, 0, stream>>>(W1, W2, W1T, W2T, (float4*)d_ws, nz4);
    k_hgemmF<<<(M_ + N_) / 16, 256, 0, stream>>>(Rinput, Sinput, W1T, W2T, a, h2, h1P, h2P, s1, s2);
    k_adjgather<<<N_ + 2 * B_ + B_ / 32, 256, 0, stream>>>(inter_adj, s1, s2, bm, rowmax, rowinv,
                                                           city_adj, prov_adj, src, BMtc, BMtp, w3, w4,
                                                           h2, h2wP);
    k_attmat<<<16384, 256, 0, stream>>>((const unsigned char*)bm, s1, s2, rowmax, rowinv, attP);
    k_gemmABC<<<2048, 256, 0, stream>>>(attP, h1P, h2P, BMtc, BMtp, w3, w4, h2wP, u_in, v_in);
    k_bnstats2<<<256, 256, 0, stream>>>(v_in, u_in, stats);
    k_bnapplyF<<<(M_ + N_) * F_ / 4 / 256, 256, 0, stream>>>(v_in, u_in, stats, g1, b1, g2, b2, v_outb, u_outb);
    k_gemmD<<<dim3(N_ / 64, M_ / 64), 256, 0, stream>>>(u_outb, v_outb, out);
}